// Round 8
// baseline (327.491 us; speedup 1.0000x reference)
//
#include <hip/hip_runtime.h>
#include <math.h>

// Problem constants (B,T,C,H) = (4, 2048, 1024, 16), D = 64.
#define B_   4
#define T_   2048
#define C_   1024
#define H_   16
#define D_   64
#define TC3  3072   // 3*C

typedef __attribute__((ext_vector_type(8))) short short8;
typedef __attribute__((ext_vector_type(4))) short short4b;
typedef __attribute__((ext_vector_type(8))) unsigned short ushortv8;
typedef __attribute__((ext_vector_type(4))) float f32x4;
typedef __attribute__((ext_vector_type(4))) __bf16 bf16x4;

__device__ __forceinline__ float bf2f(unsigned short u) {
  unsigned int x = ((unsigned int)u) << 16;
  float f; __builtin_memcpy(&f, &x, 4); return f;
}
__device__ __forceinline__ unsigned short f2bf(float f) {   // round-nearest-even
  unsigned int x; __builtin_memcpy(&x, &f, 4);
  x += 0x7fff + ((x >> 16) & 1);
  return (unsigned short)(x >> 16);
}

#define MFMA32(a, b, c) __builtin_amdgcn_mfma_f32_16x16x32_bf16(a, b, c, 0, 0, 0)
#if __has_builtin(__builtin_amdgcn_mfma_f32_16x16x16_bf16)
#define MFMA16(a, b, c) __builtin_amdgcn_mfma_f32_16x16x16_bf16(a, b, c, 0, 0, 0)
#else
#define MFMA16(a, b, c) __builtin_amdgcn_mfma_f32_16x16x16bf16_1k(a, b, c, 0, 0, 0)
#endif

#define GLOAD_LDS(gp, lp) __builtin_amdgcn_global_load_lds( \
    (const __attribute__((address_space(1))) unsigned int*)(gp), \
    (__attribute__((address_space(3))) unsigned int*)(lp), 16, 0, 0)

// softmax scale folded into q at rmsrope time: 1/sqrt(D) * log2(e)
#define QSCL (0.125f * 1.44269504088896f)

// ---------------------------------------------------------------------------
// x f32 -> bf16 (lets GEMM1 use the pure-bf16 global_load_lds staging path).
// ---------------------------------------------------------------------------
__global__ __launch_bounds__(256)
void convert_bf16(const float* __restrict__ x, unsigned short* __restrict__ xb) {
  const size_t i = ((size_t)blockIdx.x * 256 + threadIdx.x) * 8;
  float4 f0 = *(const float4*)(x + i);
  float4 f1 = *(const float4*)(x + i + 4);
  ushortv8 u = { f2bf(f0.x), f2bf(f0.y), f2bf(f0.z), f2bf(f0.w),
                 f2bf(f1.x), f2bf(f1.y), f2bf(f1.z), f2bf(f1.w) };
  *(ushortv8*)(xb + i) = u;
}

// ---------------------------------------------------------------------------
// Transpose + fp32->bf16 convert: W[K][N] f32 -> WT[N][K] bf16. 64x64 tiles.
// ---------------------------------------------------------------------------
__global__ __launch_bounds__(256)
void transpose_bf16(const float* __restrict__ W, unsigned short* __restrict__ WT,
                    int K, int N) {
  __shared__ float tile[64][65];
  const int k0 = blockIdx.y * 64, n0 = blockIdx.x * 64;
  const int r = threadIdx.x >> 4, c4 = (threadIdx.x & 15) * 4;
#pragma unroll
  for (int p = 0; p < 4; ++p) {
    int kk = p * 16 + r;
    float4 v = *(const float4*)(W + (size_t)(k0 + kk) * N + n0 + c4);
    tile[kk][c4 + 0] = v.x; tile[kk][c4 + 1] = v.y;
    tile[kk][c4 + 2] = v.z; tile[kk][c4 + 3] = v.w;
  }
  __syncthreads();
#pragma unroll
  for (int p = 0; p < 4; ++p) {
    int nn = p * 16 + r;
    ushort4 o = { f2bf(tile[c4 + 0][nn]), f2bf(tile[c4 + 1][nn]),
                  f2bf(tile[c4 + 2][nn]), f2bf(tile[c4 + 3][nn]) };
    *(ushort4*)(WT + (size_t)(n0 + nn) * K + k0 + c4) = o;
  }
}

// ---------------------------------------------------------------------------
// bf16 MFMA GEMM (validated R3-R6). A bf16 via global_load_lds.
// ---------------------------------------------------------------------------
template<bool OUT_BF16>
__global__ __launch_bounds__(256)
void gemm_mfma(const unsigned short* __restrict__ Ab,
               const unsigned short* __restrict__ Bt,
               const float* __restrict__ bias, void* __restrict__ Cv,
               int K, int lda, int ldb, int ldc) {
  __shared__ unsigned short As[128 * 64];
  __shared__ unsigned short Bs[128 * 64];
  const int tid = threadIdx.x;
  const int l = tid & 63, w = tid >> 6;
  const int m0 = blockIdx.y * 128, n0 = blockIdx.x * 128;
  const int wm = (w & 1) * 64, wn = (w >> 1) * 64;
  const int fr = l & 15, g = l >> 4;

  f32x4 acc[4][4];
#pragma unroll
  for (int i = 0; i < 4; ++i)
#pragma unroll
    for (int j = 0; j < 4; ++j) acc[i][j] = (f32x4)0.f;

  const int gr = l >> 3;
  const int gc = (l & 7) ^ gr;

  for (int kt = 0; kt < K; kt += 64) {
    __syncthreads();
#pragma unroll
    for (int q = 0; q < 4; ++q) {
      int rr = (w * 4 + q) * 8 + gr;
      GLOAD_LDS(Ab + (size_t)(m0 + rr) * lda + kt + gc * 8,
                &As[(w * 4 + q) * 512]);
      GLOAD_LDS(Bt + (size_t)(n0 + rr) * ldb + kt + gc * 8,
                &Bs[(w * 4 + q) * 512]);
    }
    __syncthreads();

#pragma unroll
    for (int s = 0; s < 2; ++s) {
      const int cofs = (((s * 4 + g) ^ (fr & 7)) << 3);
      short8 a[4], b[4];
#pragma unroll
      for (int i = 0; i < 4; ++i)
        a[i] = *(const short8*)&As[(wm + i * 16 + fr) * 64 + cofs];
#pragma unroll
      for (int j = 0; j < 4; ++j)
        b[j] = *(const short8*)&Bs[(wn + j * 16 + fr) * 64 + cofs];
#pragma unroll
      for (int i = 0; i < 4; ++i)
#pragma unroll
        for (int j = 0; j < 4; ++j)
          acc[i][j] = MFMA32(a[i], b[j], acc[i][j]);
    }
  }

#pragma unroll
  for (int j = 0; j < 4; ++j) {
    const int n = n0 + wn + j * 16 + fr;
    const float bv = bias[n];
#pragma unroll
    for (int i = 0; i < 4; ++i) {
#pragma unroll
      for (int rg = 0; rg < 4; ++rg) {
        const int m = m0 + wm + i * 16 + g * 4 + rg;
        float v = acc[i][j][rg] + bv;
        if (OUT_BF16) ((unsigned short*)Cv)[(size_t)m * ldc + n] = f2bf(v);
        else          ((float*)Cv)[(size_t)m * ldc + n] = v;
      }
    }
  }
}

// ---------------------------------------------------------------------------
// Fused per-head RMSNorm + RoPE (in-place on bf16 q,k). V handling lives in
// vtrans_kernel. Softmax scale * log2(e) folded into q (cos/sin scaled
// BEFORE the rotary combine; one rounding path either way). k unscaled.
// ---------------------------------------------------------------------------
__global__ __launch_bounds__(256)
void rmsrope_kernel(unsigned short* __restrict__ qkv) {
  const int unit = blockIdx.x * 4 + (threadIdx.x >> 6);
  const int lane = threadIdx.x & 63;
  const int b = unit / (T_ * H_);
  const int rem = unit % (T_ * H_);
  const int t = rem / H_;
  const int h = rem % H_;
  const size_t base = (size_t)(b * T_ + t) * TC3;

  const int i = lane & 31;
  const float inv = __builtin_amdgcn_exp2f(-13.2877123795494f * (float)(2 * i)
                                           * (1.0f / 64.0f));
  const float ang = (float)t * inv;
  const float cs = cosf(ang);
  const float sn = sinf(ang);
  const float csq = cs * QSCL, snq = sn * QSCL;

  {
    const size_t idx = base + h * 64 + lane;
    float q = bf2f(qkv[idx]);
    float ss = q * q;
    ss += __shfl_xor(ss, 32); ss += __shfl_xor(ss, 16);
    ss += __shfl_xor(ss, 8);  ss += __shfl_xor(ss, 4);
    ss += __shfl_xor(ss, 2);  ss += __shfl_xor(ss, 1);
    float qn = q * (1.0f / sqrtf(ss * (1.0f / 64.0f) + 1e-6f));
    float part = __shfl_xor(qn, 32);
    float out = (lane < 32) ? (qn * csq + part * snq) : (qn * csq - part * snq);
    qkv[idx] = f2bf(out);
  }
  {
    const size_t idx = base + C_ + h * 64 + lane;
    float k = bf2f(qkv[idx]);
    float ss = k * k;
    ss += __shfl_xor(ss, 32); ss += __shfl_xor(ss, 16);
    ss += __shfl_xor(ss, 8);  ss += __shfl_xor(ss, 4);
    ss += __shfl_xor(ss, 2);  ss += __shfl_xor(ss, 1);
    float kn = k * (1.0f / sqrtf(ss * (1.0f / 64.0f) + 1e-6f));
    float part = __shfl_xor(kn, 32);
    float out = (lane < 32) ? (kn * cs + part * sn) : (kn * cs - part * sn);
    qkv[idx] = f2bf(out);
  }
}

// ---------------------------------------------------------------------------
// V transpose: bf16 v-columns of qkv -> vT (B,H,D,T) bf16, with lamb applied.
// Also writes the fp32 value output (B,H,T,D) during the load phase.
// Runs BEFORE flash (flash overwrites v-columns with attn output).
// ---------------------------------------------------------------------------
__global__ __launch_bounds__(256)
void vtrans_kernel(const unsigned short* __restrict__ qkv,
                   const float* __restrict__ lambp,
                   unsigned short* __restrict__ vT,
                   float* __restrict__ valOut) {
  __shared__ float tile[64][65];
  const int t0 = blockIdx.x * 64;
  const int head = blockIdx.y;             // b*H + h
  const int b = head >> 4, h = head & 15;
  const float lamb = lambp[0];
  const int r = threadIdx.x >> 4, c4 = (threadIdx.x & 15) * 4;
#pragma unroll
  for (int p = 0; p < 4; ++p) {
    int tt = p * 16 + r;
    ushort4 raw = *(const ushort4*)(
        qkv + (size_t)(b * T_ + t0 + tt) * TC3 + 2 * C_ + h * 64 + c4);
    float4 f;
    f.x = (1.f - lamb) * bf2f(raw.x) + lamb * bf2f(raw.x);
    f.y = (1.f - lamb) * bf2f(raw.y) + lamb * bf2f(raw.y);
    f.z = (1.f - lamb) * bf2f(raw.z) + lamb * bf2f(raw.z);
    f.w = (1.f - lamb) * bf2f(raw.w) + lamb * bf2f(raw.w);
    tile[tt][c4 + 0] = f.x; tile[tt][c4 + 1] = f.y;
    tile[tt][c4 + 2] = f.z; tile[tt][c4 + 3] = f.w;
    *(float4*)(valOut + ((size_t)head * T_ + t0 + tt) * D_ + c4) = f;
  }
  __syncthreads();
#pragma unroll
  for (int p = 0; p < 4; ++p) {
    int d = p * 16 + r;
    ushort4 o = { f2bf(tile[c4 + 0][d]), f2bf(tile[c4 + 1][d]),
                  f2bf(tile[c4 + 2][d]), f2bf(tile[c4 + 3][d]) };
    *(ushort4*)(vT + ((size_t)head * D_ + d) * T_ + t0 + c4) = o;
  }
}

// ---------------------------------------------------------------------------
// MFMA flash attention — v12 = R6 pipeline with QBLK 128 -> 64.
// R7 post-mortem: occupancy 18.6% avg (grid 1024 = 4 blocks/CU; short-qt
// blocks retire and nothing replaces them -> CU decays to 1-2 blocks); the
// wave-serial chain QK-MFMA -> exp2 -> PV-MFMA is the floor and there's no
// TLP to overlap it. Fix block GRANULARITY: each wave owns 16 q-rows
// (o[1][4], qf[2]) -> VGPR ~70, grid 2048 blocks (8/CU nominal), LDS 32KB
// caps 5 resident blocks/CU = 20 waves + ~3 queued for replacement.
// Staging iters per (b,h): 272 -> 528 (2x L2 traffic, HBM ~same) — paid for
// by TLP. Ones-l-trick reverted (R7: it lengthened the MFMA critical chain,
// +2.5us); l back to hidden VALU adds + epilogue shuffle. QSCL fold kept.
// Single tile body, single-body 2-phase vmcnt(4) pipeline (R6, validated).
// ---------------------------------------------------------------------------

__device__ __forceinline__ void attn_tile(
    const unsigned short* Ks,
    const unsigned short* Vs,
    const short8 (&qf)[2], int qrow0 /* q0 + w*16 */, int k0,
    int fr, int quad, int f8,
    float &l_pt, f32x4 (&o)[4]) {
  // ---- S^T = K Q^T : C/D col = q(fr), row = key(quad*4+reg) ----
  f32x4 st[4];
#pragma unroll
  for (int j = 0; j < 4; ++j) st[j] = (f32x4)0.f;

  __builtin_amdgcn_s_setprio(1);
#pragma unroll
  for (int kc = 0; kc < 2; ++kc) {
    const int cofs = (((kc * 4 + quad) ^ f8) << 3);
#pragma unroll
    for (int j = 0; j < 4; ++j) {
      short8 kf = *(const short8*)&Ks[(j * 16 + fr) * 64 + cofs];
      st[j] = MFMA32(kf, qf[kc], st[j]);
    }
  }
  __builtin_amdgcn_s_setprio(0);

  // ---- softmax (scale pre-folded into q) + pack P into A-frags ----
  short4b pa[4];
  const int qg = qrow0 + fr;
#pragma unroll
  for (int j = 0; j < 4; ++j) {
    const int kg = k0 + j * 16 + quad * 4;
#pragma unroll
    for (int r = 0; r < 4; ++r) {
      float arg = st[j][r];
      if (kg + r > qg) arg = -INFINITY;   // branchless causal mask
      float p = __builtin_amdgcn_exp2f(arg);
      l_pt += p;
      st[j][r] = p;
    }
    bf16x4 pb = { (__bf16)st[j][0], (__bf16)st[j][1],
                  (__bf16)st[j][2], (__bf16)st[j][3] };
    pa[j] = __builtin_bit_cast(short4b, pb);
  }

  // ---- O^T += P V via 16x16x16 MFMA (P in regs, V^T b64 B-frags) ----
  __builtin_amdgcn_s_setprio(1);
#pragma unroll
  for (int c = 0; c < 4; ++c) {
    const int vofs = ((((c * 2 + (quad >> 1)) ^ f8) << 3) + (quad & 1) * 4);
#pragma unroll
    for (int jd = 0; jd < 4; ++jd) {
      short4b vf = *(const short4b*)&Vs[(jd * 16 + fr) * 64 + vofs];
      o[jd] = MFMA16(pa[c], vf, o[jd]);
    }
  }
  __builtin_amdgcn_s_setprio(0);
}

__global__ __launch_bounds__(256)
void flash_mfma(unsigned short* __restrict__ qkv,
                const unsigned short* __restrict__ vT) {
  __shared__ unsigned short KV[2][2][64 * 64];   // [buf][K=0 / V=1], 32 KB
  // Q (64x64 = 8KB) overlays KV[0][0] during the prologue only.

  // balanced work mapping across z (bijective per z; mixes long/short qt)
  const int z = blockIdx.z;
  const int xx = ((int)blockIdx.x + ((z >> 1) << 3)) & 31;
  const int qt = (z & 1) ? (31 - xx) : xx;
  const int b  = z;
  const int h  = blockIdx.y;
  const int bT = b * T_;

  const int tid = threadIdx.x;
  const int w = tid >> 6, l = tid & 63;
  const int fr = l & 15, quad = l >> 4;
  const int q0 = qt * 64;
  const int gr = l >> 3;
  const int gc = (l & 7) ^ gr;
  const int f8 = fr & 7;

#define STAGE(KS, VS, KT) do { \
  const int _k0 = (KT) * 64; \
  _Pragma("unroll") \
  for (int s_ = 0; s_ < 2; ++s_) { \
    int row_ = w * 16 + s_ * 8; \
    GLOAD_LDS(qkv + (size_t)(bT + _k0 + row_ + gr) * TC3 + C_ + h * 64 + gc * 8, \
              &(KS)[row_ * 64]); \
    GLOAD_LDS(vT + ((size_t)(b * H_ + h) * D_ + row_ + gr) * T_ + _k0 + gc * 8, \
              &(VS)[row_ * 64]); \
  } \
} while (0)

  // ---- prologue: Q (64 rows) into KV[0][0], tile0 into KV[1] ----
  unsigned short* Qb = &KV[0][0][0];
  {
    int rbase = w * 16;   // wave-uniform; each wave stages 16 rows (2 loads)
    GLOAD_LDS(qkv + (size_t)(bT + q0 + rbase + gr) * TC3 + h * 64 + gc * 8,
              Qb + rbase * 64);
    GLOAD_LDS(qkv + (size_t)(bT + q0 + rbase + 8 + gr) * TC3 + h * 64 + gc * 8,
              Qb + (rbase + 8) * 64);
  }
  STAGE(KV[1][0], KV[1][1], 0);
  __syncthreads();   // full drain: Q + tile0 staged

  // hoist iteration-invariant Q fragments (B-operand of S^T MFMA)
  short8 qf[2];
#pragma unroll
  for (int kc = 0; kc < 2; ++kc) {
    const int cofs = (((kc * 4 + quad) ^ f8) << 3);
    qf[kc] = *(const short8*)&Qb[(w * 16 + fr) * 64 + cofs];
  }
  __syncthreads();   // all waves done reading Q; KV[0] free for staging

  float l_pt = 0.f;
  f32x4 o[4];
#pragma unroll
  for (int j = 0; j < 4; ++j) o[j] = (f32x4)0.f;

  const int nk = qt + 1;
  const int qr0 = q0 + w * 16;

  int cur = 1;   // tile0 lives in KV[1]
  for (int kt = 0; kt < nk; ++kt) {
    const int nxt = cur ^ 1;
    if (kt + 1 < nk) {
      STAGE(KV[nxt][0], KV[nxt][1], kt + 1);
      asm volatile("s_waitcnt vmcnt(4)" ::: "memory");   // current tile landed
    } else {
      asm volatile("s_waitcnt vmcnt(0)" ::: "memory");   // last tile: drain
    }
    __builtin_amdgcn_s_barrier();
    asm volatile("" ::: "memory");

    attn_tile(&KV[cur][0][0], &KV[cur][1][0], qf, qr0, kt * 64,
              fr, quad, f8, l_pt, o);

    if (kt + 1 < nk) {           // WAR fence: readers done before next STAGE
      __builtin_amdgcn_s_barrier();
      asm volatile("" ::: "memory");
    }
    cur = nxt;
  }

  // ---- epilogue: reduce l over quads, store O/l (row=q via quad*4+r) ----
  {
    float lv = l_pt;
    lv += __shfl_xor(lv, 16);
    lv += __shfl_xor(lv, 32);
    float inv = 1.0f / lv;
    float invq[4];
#pragma unroll
    for (int r = 0; r < 4; ++r) invq[r] = __shfl(inv, quad * 4 + r);
#pragma unroll
    for (int jd = 0; jd < 4; ++jd) {
      const int d = jd * 16 + fr;
#pragma unroll
      for (int r = 0; r < 4; ++r) {
        const int row = qr0 + quad * 4 + r;
        qkv[(size_t)(bT + row) * TC3 + 2 * C_ + h * 64 + d] =
            f2bf(o[jd][r] * invq[r]);
      }
    }
  }
#undef STAGE
}

// ---------------------------------------------------------------------------
// Launch. d_in: x, Wqkv, bqkv, Wproj, bproj, lamb.
// d_out: out (B*T*C f32) then value (B*H*T*D f32).
// ws: qkvb 50.3MB | WqkvT 6.3MB | WprojT 2.1MB | vT 16.8MB | xb 16.8MB.
// ---------------------------------------------------------------------------
extern "C" void kernel_launch(void* const* d_in, const int* in_sizes, int n_in,
                              void* d_out, int out_size, void* d_ws, size_t ws_size,
                              hipStream_t stream) {
  const float* x     = (const float*)d_in[0];
  const float* Wqkv  = (const float*)d_in[1];
  const float* bqkv  = (const float*)d_in[2];
  const float* Wproj = (const float*)d_in[3];
  const float* bproj = (const float*)d_in[4];
  const float* lamb  = (const float*)d_in[5];

  float* out     = (float*)d_out;
  float* val_out = out + (size_t)B_ * T_ * C_;

  unsigned short* qkvb   = (unsigned short*)d_ws;                 // B*T*3C
  unsigned short* WqkvT  = qkvb + (size_t)B_ * T_ * TC3;          // 3C x C
  unsigned short* WprojT = WqkvT + (size_t)TC3 * C_;              // C x C
  unsigned short* vT     = WprojT + (size_t)C_ * C_;              // B*H*D*T
  unsigned short* xb     = vT + (size_t)B_ * H_ * D_ * T_;        // B*T*C

  convert_bf16<<<dim3((B_ * T_ * C_) / 2048), 256, 0, stream>>>(x, xb);
  transpose_bf16<<<dim3(TC3 / 64, C_ / 64), 256, 0, stream>>>(Wqkv, WqkvT, C_, TC3);
  transpose_bf16<<<dim3(C_ / 64, C_ / 64), 256, 0, stream>>>(Wproj, WprojT, C_, C_);

  gemm_mfma<true><<<dim3(TC3 / 128, (B_ * T_) / 128), 256, 0, stream>>>(
      xb, WqkvT, bqkv, qkvb, C_, C_, C_, TC3);

  rmsrope_kernel<<<dim3((B_ * T_ * H_) / 4), 256, 0, stream>>>(qkvb);

  vtrans_kernel<<<dim3(T_ / 64, B_ * H_), 256, 0, stream>>>(qkvb, lamb, vT, val_out);

  flash_mfma<<<dim3(32, H_, B_), 256, 0, stream>>>(qkvb, vT);

  gemm_mfma<false><<<dim3(C_ / 128, (B_ * T_) / 128), 256, 0, stream>>>(
      qkvb + 2 * C_, WprojT, bproj, out, C_, TC3, C_, C_);
}

// Round 9
// 318.744 us; speedup vs baseline: 1.0274x; 1.0274x over previous
//
#include <hip/hip_runtime.h>
#include <math.h>

// Problem constants (B,T,C,H) = (4, 2048, 1024, 16), D = 64.
#define B_   4
#define T_   2048
#define C_   1024
#define H_   16
#define D_   64
#define TC3  3072   // 3*C

typedef __attribute__((ext_vector_type(8))) short short8;
typedef __attribute__((ext_vector_type(4))) short short4b;
typedef __attribute__((ext_vector_type(8))) unsigned short ushortv8;
typedef __attribute__((ext_vector_type(4))) float f32x4;
typedef __attribute__((ext_vector_type(4))) __bf16 bf16x4;

__device__ __forceinline__ float bf2f(unsigned short u) {
  unsigned int x = ((unsigned int)u) << 16;
  float f; __builtin_memcpy(&f, &x, 4); return f;
}
__device__ __forceinline__ unsigned short f2bf(float f) {   // round-nearest-even
  unsigned int x; __builtin_memcpy(&x, &f, 4);
  x += 0x7fff + ((x >> 16) & 1);
  return (unsigned short)(x >> 16);
}

#define MFMA32(a, b, c) __builtin_amdgcn_mfma_f32_16x16x32_bf16(a, b, c, 0, 0, 0)
#if __has_builtin(__builtin_amdgcn_mfma_f32_16x16x16_bf16)
#define MFMA16(a, b, c) __builtin_amdgcn_mfma_f32_16x16x16_bf16(a, b, c, 0, 0, 0)
#else
#define MFMA16(a, b, c) __builtin_amdgcn_mfma_f32_16x16x16bf16_1k(a, b, c, 0, 0, 0)
#endif

#define GLOAD_LDS(gp, lp) __builtin_amdgcn_global_load_lds( \
    (const __attribute__((address_space(1))) unsigned int*)(gp), \
    (__attribute__((address_space(3))) unsigned int*)(lp), 16, 0, 0)

// softmax scale folded into q at GEMM1-epilogue time: 1/sqrt(D) * log2(e)
#define QSCL (0.125f * 1.44269504088896f)

// ---------------------------------------------------------------------------
// x f32 -> bf16 (lets GEMM1 use the pure-bf16 global_load_lds staging path).
// ---------------------------------------------------------------------------
__global__ __launch_bounds__(256)
void convert_bf16(const float* __restrict__ x, unsigned short* __restrict__ xb) {
  const size_t i = ((size_t)blockIdx.x * 256 + threadIdx.x) * 8;
  float4 f0 = *(const float4*)(x + i);
  float4 f1 = *(const float4*)(x + i + 4);
  ushortv8 u = { f2bf(f0.x), f2bf(f0.y), f2bf(f0.z), f2bf(f0.w),
                 f2bf(f1.x), f2bf(f1.y), f2bf(f1.z), f2bf(f1.w) };
  *(ushortv8*)(xb + i) = u;
}

// ---------------------------------------------------------------------------
// Transpose + fp32->bf16 convert: W[K][N] f32 -> WT[N][K] bf16. 64x64 tiles.
// ---------------------------------------------------------------------------
__global__ __launch_bounds__(256)
void transpose_bf16(const float* __restrict__ W, unsigned short* __restrict__ WT,
                    int K, int N) {
  __shared__ float tile[64][65];
  const int k0 = blockIdx.y * 64, n0 = blockIdx.x * 64;
  const int r = threadIdx.x >> 4, c4 = (threadIdx.x & 15) * 4;
#pragma unroll
  for (int p = 0; p < 4; ++p) {
    int kk = p * 16 + r;
    float4 v = *(const float4*)(W + (size_t)(k0 + kk) * N + n0 + c4);
    tile[kk][c4 + 0] = v.x; tile[kk][c4 + 1] = v.y;
    tile[kk][c4 + 2] = v.z; tile[kk][c4 + 3] = v.w;
  }
  __syncthreads();
#pragma unroll
  for (int p = 0; p < 4; ++p) {
    int nn = p * 16 + r;
    ushort4 o = { f2bf(tile[c4 + 0][nn]), f2bf(tile[c4 + 1][nn]),
                  f2bf(tile[c4 + 2][nn]), f2bf(tile[c4 + 3][nn]) };
    *(ushort4*)(WT + (size_t)(n0 + nn) * K + k0 + c4) = o;
  }
}

// ---------------------------------------------------------------------------
// bf16 MFMA GEMM (validated R3-R8). A bf16 via global_load_lds.
// FUSE_RMSROPE (GEMM1 only): for q/k tiles (n0 < 2C), apply bias + per-head
// RMSNorm + RoPE in the epilogue, on the f32 accumulator, before the single
// bf16 store. Layout facts (verified): a 128-wide n-tile = exactly 2 heads;
// per row m the 64 head-cols live in 4 regs (j) x 16 lanes (fr); RMS sum =
// sum_j acc^2 + shfl_xor{1,2,4,8} (fr bits only; same-g lanes share m);
// RoPE pair (d, d+32) = regs (j, j+2) of the SAME thread. Trig = hw
// __cosf/__sinf (error ~2e-4 << bf16 quantum). Softmax scale QSCL folded
// into cs/sn for q tiles (validated R7/R8). One bf16 rounding instead of
// two (tighter than the standalone rmsrope it replaces).
// ---------------------------------------------------------------------------
template<bool OUT_BF16, bool FUSE_RMSROPE>
__global__ __launch_bounds__(256)
void gemm_mfma(const unsigned short* __restrict__ Ab,
               const unsigned short* __restrict__ Bt,
               const float* __restrict__ bias, void* __restrict__ Cv,
               int K, int lda, int ldb, int ldc) {
  __shared__ unsigned short As[128 * 64];
  __shared__ unsigned short Bs[128 * 64];
  const int tid = threadIdx.x;
  const int l = tid & 63, w = tid >> 6;
  const int m0 = blockIdx.y * 128, n0 = blockIdx.x * 128;
  const int wm = (w & 1) * 64, wn = (w >> 1) * 64;
  const int fr = l & 15, g = l >> 4;

  f32x4 acc[4][4];
#pragma unroll
  for (int i = 0; i < 4; ++i)
#pragma unroll
    for (int j = 0; j < 4; ++j) acc[i][j] = (f32x4)0.f;

  const int gr = l >> 3;
  const int gc = (l & 7) ^ gr;

  for (int kt = 0; kt < K; kt += 64) {
    __syncthreads();
#pragma unroll
    for (int q = 0; q < 4; ++q) {
      int rr = (w * 4 + q) * 8 + gr;
      GLOAD_LDS(Ab + (size_t)(m0 + rr) * lda + kt + gc * 8,
                &As[(w * 4 + q) * 512]);
      GLOAD_LDS(Bt + (size_t)(n0 + rr) * ldb + kt + gc * 8,
                &Bs[(w * 4 + q) * 512]);
    }
    __syncthreads();

#pragma unroll
    for (int s = 0; s < 2; ++s) {
      const int cofs = (((s * 4 + g) ^ (fr & 7)) << 3);
      short8 a[4], b[4];
#pragma unroll
      for (int i = 0; i < 4; ++i)
        a[i] = *(const short8*)&As[(wm + i * 16 + fr) * 64 + cofs];
#pragma unroll
      for (int j = 0; j < 4; ++j)
        b[j] = *(const short8*)&Bs[(wn + j * 16 + fr) * 64 + cofs];
#pragma unroll
      for (int i = 0; i < 4; ++i)
#pragma unroll
        for (int j = 0; j < 4; ++j)
          acc[i][j] = MFMA32(a[i], b[j], acc[i][j]);
    }
  }

  if (FUSE_RMSROPE && n0 < 2 * C_) {
    // ---- fused bias + RMSNorm + RoPE epilogue (q/k tiles) ----
    const float qscl = (n0 < C_) ? QSCL : 1.0f;
    float bvj[4];
#pragma unroll
    for (int j = 0; j < 4; ++j) bvj[j] = bias[n0 + wn + j * 16 + fr];
#pragma unroll
    for (int i = 0; i < 4; ++i)
#pragma unroll
      for (int j = 0; j < 4; ++j)
#pragma unroll
        for (int rg = 0; rg < 4; ++rg) acc[i][j][rg] += bvj[j];

    float invf[2];
#pragma unroll
    for (int jp = 0; jp < 2; ++jp)
      invf[jp] = __builtin_amdgcn_exp2f(-13.2877123795494f *
                                        (float)(2 * (jp * 16 + fr)) *
                                        (1.0f / 64.0f));
#pragma unroll
    for (int i = 0; i < 4; ++i) {
#pragma unroll
      for (int rg = 0; rg < 4; ++rg) {
        float ss = 0.f;
#pragma unroll
        for (int j = 0; j < 4; ++j) ss += acc[i][j][rg] * acc[i][j][rg];
        ss += __shfl_xor(ss, 1); ss += __shfl_xor(ss, 2);
        ss += __shfl_xor(ss, 4); ss += __shfl_xor(ss, 8);
        const float s = 1.0f / sqrtf(ss * (1.0f / 64.0f) + 1e-6f);
        const int m = m0 + wm + i * 16 + g * 4 + rg;
        const float t = (float)(m & (T_ - 1));
#pragma unroll
        for (int jp = 0; jp < 2; ++jp) {
          float x1 = acc[i][jp][rg] * s;
          float x2 = acc[i][jp + 2][rg] * s;
          float ang = t * invf[jp];
          float cs = __cosf(ang) * qscl;
          float sn = __sinf(ang) * qscl;
          acc[i][jp][rg]     = x1 * cs + x2 * sn;
          acc[i][jp + 2][rg] = x2 * cs - x1 * sn;
        }
      }
    }
#pragma unroll
    for (int j = 0; j < 4; ++j) {
      const int n = n0 + wn + j * 16 + fr;
#pragma unroll
      for (int i = 0; i < 4; ++i)
#pragma unroll
        for (int rg = 0; rg < 4; ++rg) {
          const int m = m0 + wm + i * 16 + g * 4 + rg;
          ((unsigned short*)Cv)[(size_t)m * ldc + n] = f2bf(acc[i][j][rg]);
        }
    }
    return;
  }

  // ---- plain epilogue (v tiles of GEMM1, and all of GEMM2) ----
#pragma unroll
  for (int j = 0; j < 4; ++j) {
    const int n = n0 + wn + j * 16 + fr;
    const float bv = bias[n];
#pragma unroll
    for (int i = 0; i < 4; ++i) {
#pragma unroll
      for (int rg = 0; rg < 4; ++rg) {
        const int m = m0 + wm + i * 16 + g * 4 + rg;
        float v = acc[i][j][rg] + bv;
        if (OUT_BF16) ((unsigned short*)Cv)[(size_t)m * ldc + n] = f2bf(v);
        else          ((float*)Cv)[(size_t)m * ldc + n] = v;
      }
    }
  }
}

// ---------------------------------------------------------------------------
// V transpose: bf16 v-columns of qkv -> vT (B,H,D,T) bf16, with lamb applied.
// Also writes the fp32 value output (B,H,T,D) during the load phase.
// Runs BEFORE flash (flash overwrites v-columns with attn output).
// ---------------------------------------------------------------------------
__global__ __launch_bounds__(256)
void vtrans_kernel(const unsigned short* __restrict__ qkv,
                   const float* __restrict__ lambp,
                   unsigned short* __restrict__ vT,
                   float* __restrict__ valOut) {
  __shared__ float tile[64][65];
  const int t0 = blockIdx.x * 64;
  const int head = blockIdx.y;             // b*H + h
  const int b = head >> 4, h = head & 15;
  const float lamb = lambp[0];
  const int r = threadIdx.x >> 4, c4 = (threadIdx.x & 15) * 4;
#pragma unroll
  for (int p = 0; p < 4; ++p) {
    int tt = p * 16 + r;
    ushort4 raw = *(const ushort4*)(
        qkv + (size_t)(b * T_ + t0 + tt) * TC3 + 2 * C_ + h * 64 + c4);
    float4 f;
    f.x = (1.f - lamb) * bf2f(raw.x) + lamb * bf2f(raw.x);
    f.y = (1.f - lamb) * bf2f(raw.y) + lamb * bf2f(raw.y);
    f.z = (1.f - lamb) * bf2f(raw.z) + lamb * bf2f(raw.z);
    f.w = (1.f - lamb) * bf2f(raw.w) + lamb * bf2f(raw.w);
    tile[tt][c4 + 0] = f.x; tile[tt][c4 + 1] = f.y;
    tile[tt][c4 + 2] = f.z; tile[tt][c4 + 3] = f.w;
    *(float4*)(valOut + ((size_t)head * T_ + t0 + tt) * D_ + c4) = f;
  }
  __syncthreads();
#pragma unroll
  for (int p = 0; p < 4; ++p) {
    int d = p * 16 + r;
    ushort4 o = { f2bf(tile[c4 + 0][d]), f2bf(tile[c4 + 1][d]),
                  f2bf(tile[c4 + 2][d]), f2bf(tile[c4 + 3][d]) };
    *(ushort4*)(vT + ((size_t)head * D_ + d) * T_ + t0 + c4) = o;
  }
}

// ---------------------------------------------------------------------------
// MFMA flash attention — v13 = R6 config exactly (best validated: 90.6us,
// VGPR 84, QBLK=128, single-body 2-phase vmcnt(4) pipeline) + QSCL fold
// (validated R7/R8). R8 showed QBLK=64 ties at 91.0 but costs +20MB fetch
// and 2x bank conflicts -> revert. R4-R8 lesson: VALU cut, occupancy boost,
// latency pipeline all null at ~91us — flash is at its structural floor for
// this design; further gains need an HK-style co-designed rewrite.
// ---------------------------------------------------------------------------

__device__ __forceinline__ void attn_tile(
    const unsigned short* Ks,
    const unsigned short* Vs,
    const short8 (&qf)[2][2], int qrow0 /* q0 + w*32 */, int k0,
    int fr, int quad, int f8,
    float (&l_pt)[2], f32x4 (&o)[2][4]) {
  // ---- S^T = K Q^T : C/D col = q(fr), row = key(quad*4+reg) ----
  f32x4 st[2][4];
#pragma unroll
  for (int i = 0; i < 2; ++i)
#pragma unroll
    for (int j = 0; j < 4; ++j) st[i][j] = (f32x4)0.f;

  __builtin_amdgcn_s_setprio(1);
#pragma unroll
  for (int kc = 0; kc < 2; ++kc) {
    const int cofs = (((kc * 4 + quad) ^ f8) << 3);
#pragma unroll
    for (int j = 0; j < 4; ++j) {
      short8 kf = *(const short8*)&Ks[(j * 16 + fr) * 64 + cofs];
      st[0][j] = MFMA32(kf, qf[kc][0], st[0][j]);
      st[1][j] = MFMA32(kf, qf[kc][1], st[1][j]);
    }
  }
  __builtin_amdgcn_s_setprio(0);

  // ---- softmax (scale pre-folded into q) + pack P into A-frags ----
  short4b pa[2][4];
#pragma unroll
  for (int i = 0; i < 2; ++i) {
    const int qg = qrow0 + i * 16 + fr;
#pragma unroll
    for (int j = 0; j < 4; ++j) {
      const int kg = k0 + j * 16 + quad * 4;
#pragma unroll
      for (int r = 0; r < 4; ++r) {
        float arg = st[i][j][r];
        if (kg + r > qg) arg = -INFINITY;   // branchless causal mask
        float p = __builtin_amdgcn_exp2f(arg);
        l_pt[i] += p;
        st[i][j][r] = p;
      }
      bf16x4 pb = { (__bf16)st[i][j][0], (__bf16)st[i][j][1],
                    (__bf16)st[i][j][2], (__bf16)st[i][j][3] };
      pa[i][j] = __builtin_bit_cast(short4b, pb);
    }
  }

  // ---- O^T += P V via 16x16x16 MFMA (P in regs, V^T b64 B-frags) ----
  __builtin_amdgcn_s_setprio(1);
#pragma unroll
  for (int c = 0; c < 4; ++c) {
    const int vofs = ((((c * 2 + (quad >> 1)) ^ f8) << 3) + (quad & 1) * 4);
#pragma unroll
    for (int jd = 0; jd < 4; ++jd) {
      short4b vf = *(const short4b*)&Vs[(jd * 16 + fr) * 64 + vofs];
      o[0][jd] = MFMA16(pa[0][c], vf, o[0][jd]);
      o[1][jd] = MFMA16(pa[1][c], vf, o[1][jd]);
    }
  }
  __builtin_amdgcn_s_setprio(0);
}

__device__ __forceinline__ void attn_store(
    unsigned short* __restrict__ qkv, int bT, int h, int qrow0,
    int fr, int quad, float (&l_pt)[2], f32x4 (&o)[2][4]) {
#pragma unroll
  for (int i = 0; i < 2; ++i) {
    float lv = l_pt[i];
    lv += __shfl_xor(lv, 16);
    lv += __shfl_xor(lv, 32);
    float inv = 1.0f / lv;
    float invq[4];
#pragma unroll
    for (int r = 0; r < 4; ++r) invq[r] = __shfl(inv, quad * 4 + r);
#pragma unroll
    for (int jd = 0; jd < 4; ++jd) {
      const int d = jd * 16 + fr;
#pragma unroll
      for (int r = 0; r < 4; ++r) {
        const int row = qrow0 + i * 16 + quad * 4 + r;
        qkv[(size_t)(bT + row) * TC3 + 2 * C_ + h * 64 + d] =
            f2bf(o[i][jd][r] * invq[r]);
      }
    }
  }
}

__global__ __launch_bounds__(256)
void flash_mfma(unsigned short* __restrict__ qkv,
                const unsigned short* __restrict__ vT) {
  __shared__ unsigned short KV[2][2][64 * 64];   // [buf][K=0 / V=1], 32 KB
  // Q (128x64 = 16KB) overlays KV[0] during the prologue only.

  // balanced work mapping: qts {x, 15-x, (x+8)&15, 15-((x+8)&15)} per CU
  const int z = blockIdx.z;
  const int xx = ((int)blockIdx.x + ((z >> 1) << 3)) & 15;
  const int qt = (z & 1) ? (15 - xx) : xx;
  const int b  = z;
  const int h  = blockIdx.y;
  const int bT = b * T_;

  const int tid = threadIdx.x;
  const int w = tid >> 6, l = tid & 63;
  const int fr = l & 15, quad = l >> 4;
  const int q0 = qt * 128;
  const int gr = l >> 3;
  const int gc = (l & 7) ^ gr;
  const int f8 = fr & 7;

#define STAGE(KS, VS, KT) do { \
  const int _k0 = (KT) * 64; \
  _Pragma("unroll") \
  for (int s_ = 0; s_ < 2; ++s_) { \
    int row_ = w * 16 + s_ * 8; \
    GLOAD_LDS(qkv + (size_t)(bT + _k0 + row_ + gr) * TC3 + C_ + h * 64 + gc * 8, \
              &(KS)[row_ * 64]); \
    GLOAD_LDS(vT + ((size_t)(b * H_ + h) * D_ + row_ + gr) * T_ + _k0 + gc * 8, \
              &(VS)[row_ * 64]); \
  } \
} while (0)

  // ---- prologue: Q into KV[0] (linear 8192 shorts), tile0 into KV[1] ----
  unsigned short* Qb = &KV[0][0][0];
#pragma unroll
  for (int s = 0; s < 4; ++s) {
    int rbase = w * 32 + s * 8;   // wave-uniform
    GLOAD_LDS(qkv + (size_t)(bT + q0 + rbase + gr) * TC3 + h * 64 + gc * 8,
              Qb + rbase * 64);
  }
  STAGE(KV[1][0], KV[1][1], 0);
  __syncthreads();   // full drain: Q + tile0 staged

  // hoist iteration-invariant Q fragments (B-operand of S^T MFMA)
  short8 qf[2][2];
#pragma unroll
  for (int kc = 0; kc < 2; ++kc) {
    const int cofs = (((kc * 4 + quad) ^ f8) << 3);
    qf[kc][0] = *(const short8*)&Qb[(w * 32 + fr) * 64 + cofs];
    qf[kc][1] = *(const short8*)&Qb[(w * 32 + 16 + fr) * 64 + cofs];
  }
  __syncthreads();   // all waves done reading Q; KV[0] free for staging

  float l_pt[2] = {0.f, 0.f};
  f32x4 o[2][4];
#pragma unroll
  for (int i = 0; i < 2; ++i)
#pragma unroll
    for (int j = 0; j < 4; ++j) o[i][j] = (f32x4)0.f;

  const int nk = 2 * qt + 2;
  const int qr0 = q0 + w * 32;

  int cur = 1;   // tile0 lives in KV[1]
  for (int kt = 0; kt < nk; ++kt) {
    const int nxt = cur ^ 1;
    if (kt + 1 < nk) {
      STAGE(KV[nxt][0], KV[nxt][1], kt + 1);
      asm volatile("s_waitcnt vmcnt(4)" ::: "memory");   // current tile landed
    } else {
      asm volatile("s_waitcnt vmcnt(0)" ::: "memory");   // last tile: drain
    }
    __builtin_amdgcn_s_barrier();
    asm volatile("" ::: "memory");

    attn_tile(&KV[cur][0][0], &KV[cur][1][0], qf, qr0, kt * 64,
              fr, quad, f8, l_pt, o);

    if (kt + 1 < nk) {           // WAR fence: readers done before next STAGE
      __builtin_amdgcn_s_barrier();
      asm volatile("" ::: "memory");
    }
    cur = nxt;
  }

  // ---- epilogue: reduce l over quads, store O/l (row=q via quad*4+r) ----
  attn_store(qkv, bT, h, qr0, fr, quad, l_pt, o);
#undef STAGE
}

// ---------------------------------------------------------------------------
// Launch. d_in: x, Wqkv, bqkv, Wproj, bproj, lamb.
// d_out: out (B*T*C f32) then value (B*H*T*D f32).
// ws: qkvb 50.3MB | WqkvT 6.3MB | WprojT 2.1MB | vT 16.8MB | xb 16.8MB.
// R9: rmsrope_kernel removed — fused into GEMM1's epilogue.
// ---------------------------------------------------------------------------
extern "C" void kernel_launch(void* const* d_in, const int* in_sizes, int n_in,
                              void* d_out, int out_size, void* d_ws, size_t ws_size,
                              hipStream_t stream) {
  const float* x     = (const float*)d_in[0];
  const float* Wqkv  = (const float*)d_in[1];
  const float* bqkv  = (const float*)d_in[2];
  const float* Wproj = (const float*)d_in[3];
  const float* bproj = (const float*)d_in[4];
  const float* lamb  = (const float*)d_in[5];

  float* out     = (float*)d_out;
  float* val_out = out + (size_t)B_ * T_ * C_;

  unsigned short* qkvb   = (unsigned short*)d_ws;                 // B*T*3C
  unsigned short* WqkvT  = qkvb + (size_t)B_ * T_ * TC3;          // 3C x C
  unsigned short* WprojT = WqkvT + (size_t)TC3 * C_;              // C x C
  unsigned short* vT     = WprojT + (size_t)C_ * C_;              // B*H*D*T
  unsigned short* xb     = vT + (size_t)B_ * H_ * D_ * T_;        // B*T*C

  convert_bf16<<<dim3((B_ * T_ * C_) / 2048), 256, 0, stream>>>(x, xb);
  transpose_bf16<<<dim3(TC3 / 64, C_ / 64), 256, 0, stream>>>(Wqkv, WqkvT, C_, TC3);
  transpose_bf16<<<dim3(C_ / 64, C_ / 64), 256, 0, stream>>>(Wproj, WprojT, C_, C_);

  gemm_mfma<true, true><<<dim3(TC3 / 128, (B_ * T_) / 128), 256, 0, stream>>>(
      xb, WqkvT, bqkv, qkvb, C_, C_, C_, TC3);

  vtrans_kernel<<<dim3(T_ / 64, B_ * H_), 256, 0, stream>>>(qkvb, lamb, vT, val_out);

  flash_mfma<<<dim3(16, H_, B_), 256, 0, stream>>>(qkvb, vT);

  gemm_mfma<false, false><<<dim3(C_ / 128, (B_ * T_) / 128), 256, 0, stream>>>(
      qkvb + 2 * C_, WprojT, bproj, out, C_, TC3, C_, C_);
}

// Round 10
// 316.012 us; speedup vs baseline: 1.0363x; 1.0086x over previous
//
#include <hip/hip_runtime.h>
#include <math.h>

// Problem constants (B,T,C,H) = (4, 2048, 1024, 16), D = 64.
#define B_   4
#define T_   2048
#define C_   1024
#define H_   16
#define D_   64
#define TC3  3072   // 3*C

typedef __attribute__((ext_vector_type(8))) short short8;
typedef __attribute__((ext_vector_type(4))) short short4b;
typedef __attribute__((ext_vector_type(8))) unsigned short ushortv8;
typedef __attribute__((ext_vector_type(4))) float f32x4;
typedef __attribute__((ext_vector_type(4))) __bf16 bf16x4;

__device__ __forceinline__ float bf2f(unsigned short u) {
  unsigned int x = ((unsigned int)u) << 16;
  float f; __builtin_memcpy(&f, &x, 4); return f;
}
__device__ __forceinline__ unsigned short f2bf(float f) {   // round-nearest-even
  unsigned int x; __builtin_memcpy(&x, &f, 4);
  x += 0x7fff + ((x >> 16) & 1);
  return (unsigned short)(x >> 16);
}

#define MFMA32(a, b, c) __builtin_amdgcn_mfma_f32_16x16x32_bf16(a, b, c, 0, 0, 0)
#if __has_builtin(__builtin_amdgcn_mfma_f32_16x16x16_bf16)
#define MFMA16(a, b, c) __builtin_amdgcn_mfma_f32_16x16x16_bf16(a, b, c, 0, 0, 0)
#else
#define MFMA16(a, b, c) __builtin_amdgcn_mfma_f32_16x16x16bf16_1k(a, b, c, 0, 0, 0)
#endif

#define GLOAD_LDS(gp, lp) __builtin_amdgcn_global_load_lds( \
    (const __attribute__((address_space(1))) unsigned int*)(gp), \
    (__attribute__((address_space(3))) unsigned int*)(lp), 16, 0, 0)

// softmax scale folded into q at GEMM1-epilogue time: 1/sqrt(D) * log2(e)
#define QSCL (0.125f * 1.44269504088896f)

// ---------------------------------------------------------------------------
// x f32 -> bf16 (lets GEMM1 use the pure-bf16 global_load_lds staging path).
// ---------------------------------------------------------------------------
__global__ __launch_bounds__(256)
void convert_bf16(const float* __restrict__ x, unsigned short* __restrict__ xb) {
  const size_t i = ((size_t)blockIdx.x * 256 + threadIdx.x) * 8;
  float4 f0 = *(const float4*)(x + i);
  float4 f1 = *(const float4*)(x + i + 4);
  ushortv8 u = { f2bf(f0.x), f2bf(f0.y), f2bf(f0.z), f2bf(f0.w),
                 f2bf(f1.x), f2bf(f1.y), f2bf(f1.z), f2bf(f1.w) };
  *(ushortv8*)(xb + i) = u;
}

// ---------------------------------------------------------------------------
// Transpose + fp32->bf16 convert: W[K][N] f32 -> WT[N][K] bf16. 64x64 tiles.
// ---------------------------------------------------------------------------
__global__ __launch_bounds__(256)
void transpose_bf16(const float* __restrict__ W, unsigned short* __restrict__ WT,
                    int K, int N) {
  __shared__ float tile[64][65];
  const int k0 = blockIdx.y * 64, n0 = blockIdx.x * 64;
  const int r = threadIdx.x >> 4, c4 = (threadIdx.x & 15) * 4;
#pragma unroll
  for (int p = 0; p < 4; ++p) {
    int kk = p * 16 + r;
    float4 v = *(const float4*)(W + (size_t)(k0 + kk) * N + n0 + c4);
    tile[kk][c4 + 0] = v.x; tile[kk][c4 + 1] = v.y;
    tile[kk][c4 + 2] = v.z; tile[kk][c4 + 3] = v.w;
  }
  __syncthreads();
#pragma unroll
  for (int p = 0; p < 4; ++p) {
    int nn = p * 16 + r;
    ushort4 o = { f2bf(tile[c4 + 0][nn]), f2bf(tile[c4 + 1][nn]),
                  f2bf(tile[c4 + 2][nn]), f2bf(tile[c4 + 3][nn]) };
    *(ushort4*)(WT + (size_t)(n0 + nn) * K + k0 + c4) = o;
  }
}

// ---------------------------------------------------------------------------
// bf16 MFMA GEMM (validated R3-R9). A bf16 via global_load_lds.
// FUSE_RMSROPE (GEMM1 only, validated R9): for q/k tiles (n0 < 2C), apply
// bias + per-head RMSNorm + RoPE in the epilogue on the f32 accumulator.
// ---------------------------------------------------------------------------
template<bool OUT_BF16, bool FUSE_RMSROPE>
__global__ __launch_bounds__(256)
void gemm_mfma(const unsigned short* __restrict__ Ab,
               const unsigned short* __restrict__ Bt,
               const float* __restrict__ bias, void* __restrict__ Cv,
               int K, int lda, int ldb, int ldc) {
  __shared__ unsigned short As[128 * 64];
  __shared__ unsigned short Bs[128 * 64];
  const int tid = threadIdx.x;
  const int l = tid & 63, w = tid >> 6;
  const int m0 = blockIdx.y * 128, n0 = blockIdx.x * 128;
  const int wm = (w & 1) * 64, wn = (w >> 1) * 64;
  const int fr = l & 15, g = l >> 4;

  f32x4 acc[4][4];
#pragma unroll
  for (int i = 0; i < 4; ++i)
#pragma unroll
    for (int j = 0; j < 4; ++j) acc[i][j] = (f32x4)0.f;

  const int gr = l >> 3;
  const int gc = (l & 7) ^ gr;

  for (int kt = 0; kt < K; kt += 64) {
    __syncthreads();
#pragma unroll
    for (int q = 0; q < 4; ++q) {
      int rr = (w * 4 + q) * 8 + gr;
      GLOAD_LDS(Ab + (size_t)(m0 + rr) * lda + kt + gc * 8,
                &As[(w * 4 + q) * 512]);
      GLOAD_LDS(Bt + (size_t)(n0 + rr) * ldb + kt + gc * 8,
                &Bs[(w * 4 + q) * 512]);
    }
    __syncthreads();

#pragma unroll
    for (int s = 0; s < 2; ++s) {
      const int cofs = (((s * 4 + g) ^ (fr & 7)) << 3);
      short8 a[4], b[4];
#pragma unroll
      for (int i = 0; i < 4; ++i)
        a[i] = *(const short8*)&As[(wm + i * 16 + fr) * 64 + cofs];
#pragma unroll
      for (int j = 0; j < 4; ++j)
        b[j] = *(const short8*)&Bs[(wn + j * 16 + fr) * 64 + cofs];
#pragma unroll
      for (int i = 0; i < 4; ++i)
#pragma unroll
        for (int j = 0; j < 4; ++j)
          acc[i][j] = MFMA32(a[i], b[j], acc[i][j]);
    }
  }

  if (FUSE_RMSROPE && n0 < 2 * C_) {
    // ---- fused bias + RMSNorm + RoPE epilogue (q/k tiles) ----
    const float qscl = (n0 < C_) ? QSCL : 1.0f;
    float bvj[4];
#pragma unroll
    for (int j = 0; j < 4; ++j) bvj[j] = bias[n0 + wn + j * 16 + fr];
#pragma unroll
    for (int i = 0; i < 4; ++i)
#pragma unroll
      for (int j = 0; j < 4; ++j)
#pragma unroll
        for (int rg = 0; rg < 4; ++rg) acc[i][j][rg] += bvj[j];

    float invf[2];
#pragma unroll
    for (int jp = 0; jp < 2; ++jp)
      invf[jp] = __builtin_amdgcn_exp2f(-13.2877123795494f *
                                        (float)(2 * (jp * 16 + fr)) *
                                        (1.0f / 64.0f));
#pragma unroll
    for (int i = 0; i < 4; ++i) {
#pragma unroll
      for (int rg = 0; rg < 4; ++rg) {
        float ss = 0.f;
#pragma unroll
        for (int j = 0; j < 4; ++j) ss += acc[i][j][rg] * acc[i][j][rg];
        ss += __shfl_xor(ss, 1); ss += __shfl_xor(ss, 2);
        ss += __shfl_xor(ss, 4); ss += __shfl_xor(ss, 8);
        const float s = 1.0f / sqrtf(ss * (1.0f / 64.0f) + 1e-6f);
        const int m = m0 + wm + i * 16 + g * 4 + rg;
        const float t = (float)(m & (T_ - 1));
#pragma unroll
        for (int jp = 0; jp < 2; ++jp) {
          float x1 = acc[i][jp][rg] * s;
          float x2 = acc[i][jp + 2][rg] * s;
          float ang = t * invf[jp];
          float cs = __cosf(ang) * qscl;
          float sn = __sinf(ang) * qscl;
          acc[i][jp][rg]     = x1 * cs + x2 * sn;
          acc[i][jp + 2][rg] = x2 * cs - x1 * sn;
        }
      }
    }
#pragma unroll
    for (int j = 0; j < 4; ++j) {
      const int n = n0 + wn + j * 16 + fr;
#pragma unroll
      for (int i = 0; i < 4; ++i)
#pragma unroll
        for (int rg = 0; rg < 4; ++rg) {
          const int m = m0 + wm + i * 16 + g * 4 + rg;
          ((unsigned short*)Cv)[(size_t)m * ldc + n] = f2bf(acc[i][j][rg]);
        }
    }
    return;
  }

  // ---- plain epilogue (v tiles of GEMM1, and all of GEMM2) ----
#pragma unroll
  for (int j = 0; j < 4; ++j) {
    const int n = n0 + wn + j * 16 + fr;
    const float bv = bias[n];
#pragma unroll
    for (int i = 0; i < 4; ++i) {
#pragma unroll
      for (int rg = 0; rg < 4; ++rg) {
        const int m = m0 + wm + i * 16 + g * 4 + rg;
        float v = acc[i][j][rg] + bv;
        if (OUT_BF16) ((unsigned short*)Cv)[(size_t)m * ldc + n] = f2bf(v);
        else          ((float*)Cv)[(size_t)m * ldc + n] = v;
      }
    }
  }
}

// ---------------------------------------------------------------------------
// V transpose: bf16 v-columns of qkv -> vT (B,H,D,T) bf16, with lamb applied.
// Also writes the fp32 value output (B,H,T,D) during the load phase.
// Runs BEFORE flash (flash overwrites v-columns with attn output).
// ---------------------------------------------------------------------------
__global__ __launch_bounds__(256)
void vtrans_kernel(const unsigned short* __restrict__ qkv,
                   const float* __restrict__ lambp,
                   unsigned short* __restrict__ vT,
                   float* __restrict__ valOut) {
  __shared__ float tile[64][65];
  const int t0 = blockIdx.x * 64;
  const int head = blockIdx.y;             // b*H + h
  const int b = head >> 4, h = head & 15;
  const float lamb = lambp[0];
  const int r = threadIdx.x >> 4, c4 = (threadIdx.x & 15) * 4;
#pragma unroll
  for (int p = 0; p < 4; ++p) {
    int tt = p * 16 + r;
    ushort4 raw = *(const ushort4*)(
        qkv + (size_t)(b * T_ + t0 + tt) * TC3 + 2 * C_ + h * 64 + c4);
    float4 f;
    f.x = (1.f - lamb) * bf2f(raw.x) + lamb * bf2f(raw.x);
    f.y = (1.f - lamb) * bf2f(raw.y) + lamb * bf2f(raw.y);
    f.z = (1.f - lamb) * bf2f(raw.z) + lamb * bf2f(raw.z);
    f.w = (1.f - lamb) * bf2f(raw.w) + lamb * bf2f(raw.w);
    tile[tt][c4 + 0] = f.x; tile[tt][c4 + 1] = f.y;
    tile[tt][c4 + 2] = f.z; tile[tt][c4 + 3] = f.w;
    *(float4*)(valOut + ((size_t)head * T_ + t0 + tt) * D_ + c4) = f;
  }
  __syncthreads();
#pragma unroll
  for (int p = 0; p < 4; ++p) {
    int d = p * 16 + r;
    ushort4 o = { f2bf(tile[c4 + 0][d]), f2bf(tile[c4 + 1][d]),
                  f2bf(tile[c4 + 2][d]), f2bf(tile[c4 + 3][d]) };
    *(ushort4*)(vT + ((size_t)head * D_ + d) * T_ + t0 + c4) = o;
  }
}

// ---------------------------------------------------------------------------
// MFMA flash attention — v14 = R9 source + __launch_bounds__(256, 6).
// R9 post-mortem: identical algorithm (strict op-subset of R6's) compiled
// to VGPR 100 instead of 84 (TU context changed: rmsrope deleted, gemm
// templated -> regalloc noise, rule #19). 512-reg file: 84 -> 6 waves/SIMD,
// 100 -> 5 waves/SIMD — a hidden -17% residency step; occ 18.6->14.6%, dur
// 90.6->106.7us. Flash dur has tracked VGPR monotonically across 5 builds.
// Fix: pin the budget. launch_bounds 2nd arg = min waves/EU; 6 waves/EU
// => VGPR cap floor(512/6) = 85. R6 proved this algorithm fits in 84 with
// zero spill at best-ever dur.
// ---------------------------------------------------------------------------

__device__ __forceinline__ void attn_tile(
    const unsigned short* Ks,
    const unsigned short* Vs,
    const short8 (&qf)[2][2], int qrow0 /* q0 + w*32 */, int k0,
    int fr, int quad, int f8,
    float (&l_pt)[2], f32x4 (&o)[2][4]) {
  // ---- S^T = K Q^T : C/D col = q(fr), row = key(quad*4+reg) ----
  f32x4 st[2][4];
#pragma unroll
  for (int i = 0; i < 2; ++i)
#pragma unroll
    for (int j = 0; j < 4; ++j) st[i][j] = (f32x4)0.f;

  __builtin_amdgcn_s_setprio(1);
#pragma unroll
  for (int kc = 0; kc < 2; ++kc) {
    const int cofs = (((kc * 4 + quad) ^ f8) << 3);
#pragma unroll
    for (int j = 0; j < 4; ++j) {
      short8 kf = *(const short8*)&Ks[(j * 16 + fr) * 64 + cofs];
      st[0][j] = MFMA32(kf, qf[kc][0], st[0][j]);
      st[1][j] = MFMA32(kf, qf[kc][1], st[1][j]);
    }
  }
  __builtin_amdgcn_s_setprio(0);

  // ---- softmax (scale pre-folded into q) + pack P into A-frags ----
  short4b pa[2][4];
#pragma unroll
  for (int i = 0; i < 2; ++i) {
    const int qg = qrow0 + i * 16 + fr;
#pragma unroll
    for (int j = 0; j < 4; ++j) {
      const int kg = k0 + j * 16 + quad * 4;
#pragma unroll
      for (int r = 0; r < 4; ++r) {
        float arg = st[i][j][r];
        if (kg + r > qg) arg = -INFINITY;   // branchless causal mask
        float p = __builtin_amdgcn_exp2f(arg);
        l_pt[i] += p;
        st[i][j][r] = p;
      }
      bf16x4 pb = { (__bf16)st[i][j][0], (__bf16)st[i][j][1],
                    (__bf16)st[i][j][2], (__bf16)st[i][j][3] };
      pa[i][j] = __builtin_bit_cast(short4b, pb);
    }
  }

  // ---- O^T += P V via 16x16x16 MFMA (P in regs, V^T b64 B-frags) ----
  __builtin_amdgcn_s_setprio(1);
#pragma unroll
  for (int c = 0; c < 4; ++c) {
    const int vofs = ((((c * 2 + (quad >> 1)) ^ f8) << 3) + (quad & 1) * 4);
#pragma unroll
    for (int jd = 0; jd < 4; ++jd) {
      short4b vf = *(const short4b*)&Vs[(jd * 16 + fr) * 64 + vofs];
      o[0][jd] = MFMA16(pa[0][c], vf, o[0][jd]);
      o[1][jd] = MFMA16(pa[1][c], vf, o[1][jd]);
    }
  }
  __builtin_amdgcn_s_setprio(0);
}

__device__ __forceinline__ void attn_store(
    unsigned short* __restrict__ qkv, int bT, int h, int qrow0,
    int fr, int quad, float (&l_pt)[2], f32x4 (&o)[2][4]) {
#pragma unroll
  for (int i = 0; i < 2; ++i) {
    float lv = l_pt[i];
    lv += __shfl_xor(lv, 16);
    lv += __shfl_xor(lv, 32);
    float inv = 1.0f / lv;
    float invq[4];
#pragma unroll
    for (int r = 0; r < 4; ++r) invq[r] = __shfl(inv, quad * 4 + r);
#pragma unroll
    for (int jd = 0; jd < 4; ++jd) {
      const int d = jd * 16 + fr;
#pragma unroll
      for (int r = 0; r < 4; ++r) {
        const int row = qrow0 + i * 16 + quad * 4 + r;
        qkv[(size_t)(bT + row) * TC3 + 2 * C_ + h * 64 + d] =
            f2bf(o[i][jd][r] * invq[r]);
      }
    }
  }
}

__global__ __launch_bounds__(256, 6)
void flash_mfma(unsigned short* __restrict__ qkv,
                const unsigned short* __restrict__ vT) {
  __shared__ unsigned short KV[2][2][64 * 64];   // [buf][K=0 / V=1], 32 KB
  // Q (128x64 = 16KB) overlays KV[0] during the prologue only.

  // balanced work mapping: qts {x, 15-x, (x+8)&15, 15-((x+8)&15)} per CU
  const int z = blockIdx.z;
  const int xx = ((int)blockIdx.x + ((z >> 1) << 3)) & 15;
  const int qt = (z & 1) ? (15 - xx) : xx;
  const int b  = z;
  const int h  = blockIdx.y;
  const int bT = b * T_;

  const int tid = threadIdx.x;
  const int w = tid >> 6, l = tid & 63;
  const int fr = l & 15, quad = l >> 4;
  const int q0 = qt * 128;
  const int gr = l >> 3;
  const int gc = (l & 7) ^ gr;
  const int f8 = fr & 7;

#define STAGE(KS, VS, KT) do { \
  const int _k0 = (KT) * 64; \
  _Pragma("unroll") \
  for (int s_ = 0; s_ < 2; ++s_) { \
    int row_ = w * 16 + s_ * 8; \
    GLOAD_LDS(qkv + (size_t)(bT + _k0 + row_ + gr) * TC3 + C_ + h * 64 + gc * 8, \
              &(KS)[row_ * 64]); \
    GLOAD_LDS(vT + ((size_t)(b * H_ + h) * D_ + row_ + gr) * T_ + _k0 + gc * 8, \
              &(VS)[row_ * 64]); \
  } \
} while (0)

  // ---- prologue: Q into KV[0] (linear 8192 shorts), tile0 into KV[1] ----
  unsigned short* Qb = &KV[0][0][0];
#pragma unroll
  for (int s = 0; s < 4; ++s) {
    int rbase = w * 32 + s * 8;   // wave-uniform
    GLOAD_LDS(qkv + (size_t)(bT + q0 + rbase + gr) * TC3 + h * 64 + gc * 8,
              Qb + rbase * 64);
  }
  STAGE(KV[1][0], KV[1][1], 0);
  __syncthreads();   // full drain: Q + tile0 staged

  // hoist iteration-invariant Q fragments (B-operand of S^T MFMA)
  short8 qf[2][2];
#pragma unroll
  for (int kc = 0; kc < 2; ++kc) {
    const int cofs = (((kc * 4 + quad) ^ f8) << 3);
    qf[kc][0] = *(const short8*)&Qb[(w * 32 + fr) * 64 + cofs];
    qf[kc][1] = *(const short8*)&Qb[(w * 32 + 16 + fr) * 64 + cofs];
  }
  __syncthreads();   // all waves done reading Q; KV[0] free for staging

  float l_pt[2] = {0.f, 0.f};
  f32x4 o[2][4];
#pragma unroll
  for (int i = 0; i < 2; ++i)
#pragma unroll
    for (int j = 0; j < 4; ++j) o[i][j] = (f32x4)0.f;

  const int nk = 2 * qt + 2;
  const int qr0 = q0 + w * 32;

  int cur = 1;   // tile0 lives in KV[1]
  for (int kt = 0; kt < nk; ++kt) {
    const int nxt = cur ^ 1;
    if (kt + 1 < nk) {
      STAGE(KV[nxt][0], KV[nxt][1], kt + 1);
      asm volatile("s_waitcnt vmcnt(4)" ::: "memory");   // current tile landed
    } else {
      asm volatile("s_waitcnt vmcnt(0)" ::: "memory");   // last tile: drain
    }
    __builtin_amdgcn_s_barrier();
    asm volatile("" ::: "memory");

    attn_tile(&KV[cur][0][0], &KV[cur][1][0], qf, qr0, kt * 64,
              fr, quad, f8, l_pt, o);

    if (kt + 1 < nk) {           // WAR fence: readers done before next STAGE
      __builtin_amdgcn_s_barrier();
      asm volatile("" ::: "memory");
    }
    cur = nxt;
  }

  // ---- epilogue: reduce l over quads, store O/l (row=q via quad*4+r) ----
  attn_store(qkv, bT, h, qr0, fr, quad, l_pt, o);
#undef STAGE
}

// ---------------------------------------------------------------------------
// Launch. d_in: x, Wqkv, bqkv, Wproj, bproj, lamb.
// d_out: out (B*T*C f32) then value (B*H*T*D f32).
// ws: qkvb 50.3MB | WqkvT 6.3MB | WprojT 2.1MB | vT 16.8MB | xb 16.8MB.
// rmsrope fused into GEMM1's epilogue (R9, validated).
// ---------------------------------------------------------------------------
extern "C" void kernel_launch(void* const* d_in, const int* in_sizes, int n_in,
                              void* d_out, int out_size, void* d_ws, size_t ws_size,
                              hipStream_t stream) {
  const float* x     = (const float*)d_in[0];
  const float* Wqkv  = (const float*)d_in[1];
  const float* bqkv  = (const float*)d_in[2];
  const float* Wproj = (const float*)d_in[3];
  const float* bproj = (const float*)d_in[4];
  const float* lamb  = (const float*)d_in[5];

  float* out     = (float*)d_out;
  float* val_out = out + (size_t)B_ * T_ * C_;

  unsigned short* qkvb   = (unsigned short*)d_ws;                 // B*T*3C
  unsigned short* WqkvT  = qkvb + (size_t)B_ * T_ * TC3;          // 3C x C
  unsigned short* WprojT = WqkvT + (size_t)TC3 * C_;              // C x C
  unsigned short* vT     = WprojT + (size_t)C_ * C_;              // B*H*D*T
  unsigned short* xb     = vT + (size_t)B_ * H_ * D_ * T_;        // B*T*C

  convert_bf16<<<dim3((B_ * T_ * C_) / 2048), 256, 0, stream>>>(x, xb);
  transpose_bf16<<<dim3(TC3 / 64, C_ / 64), 256, 0, stream>>>(Wqkv, WqkvT, C_, TC3);
  transpose_bf16<<<dim3(C_ / 64, C_ / 64), 256, 0, stream>>>(Wproj, WprojT, C_, C_);

  gemm_mfma<true, true><<<dim3(TC3 / 128, (B_ * T_) / 128), 256, 0, stream>>>(
      xb, WqkvT, bqkv, qkvb, C_, C_, C_, TC3);

  vtrans_kernel<<<dim3(T_ / 64, B_ * H_), 256, 0, stream>>>(qkvb, lamb, vT, val_out);

  flash_mfma<<<dim3(16, H_, B_), 256, 0, stream>>>(qkvb, vT);

  gemm_mfma<false, false><<<dim3(C_ / 128, (B_ * T_) / 128), 256, 0, stream>>>(
      qkvb + 2 * C_, WprojT, bproj, out, C_, TC3, C_, C_);
}

// Round 11
// 299.921 us; speedup vs baseline: 1.0919x; 1.0537x over previous
//
#include <hip/hip_runtime.h>
#include <math.h>

// Problem constants (B,T,C,H) = (4, 2048, 1024, 16), D = 64.
#define B_   4
#define T_   2048
#define C_   1024
#define H_   16
#define D_   64
#define TC3  3072   // 3*C

typedef __attribute__((ext_vector_type(8))) short short8;
typedef __attribute__((ext_vector_type(4))) short short4b;
typedef __attribute__((ext_vector_type(8))) unsigned short ushortv8;
typedef __attribute__((ext_vector_type(4))) float f32x4;
typedef __attribute__((ext_vector_type(4))) __bf16 bf16x4;

__device__ __forceinline__ float bf2f(unsigned short u) {
  unsigned int x = ((unsigned int)u) << 16;
  float f; __builtin_memcpy(&f, &x, 4); return f;
}
__device__ __forceinline__ unsigned short f2bf(float f) {   // round-nearest-even
  unsigned int x; __builtin_memcpy(&x, &f, 4);
  x += 0x7fff + ((x >> 16) & 1);
  return (unsigned short)(x >> 16);
}

#define MFMA32(a, b, c) __builtin_amdgcn_mfma_f32_16x16x32_bf16(a, b, c, 0, 0, 0)
#if __has_builtin(__builtin_amdgcn_mfma_f32_16x16x16_bf16)
#define MFMA16(a, b, c) __builtin_amdgcn_mfma_f32_16x16x16_bf16(a, b, c, 0, 0, 0)
#else
#define MFMA16(a, b, c) __builtin_amdgcn_mfma_f32_16x16x16bf16_1k(a, b, c, 0, 0, 0)
#endif

#define GLOAD_LDS(gp, lp) __builtin_amdgcn_global_load_lds( \
    (const __attribute__((address_space(1))) unsigned int*)(gp), \
    (__attribute__((address_space(3))) unsigned int*)(lp), 16, 0, 0)

// ---------------------------------------------------------------------------
// x f32 -> bf16 (lets GEMM1 use the pure-bf16 global_load_lds staging path).
// ---------------------------------------------------------------------------
__global__ __launch_bounds__(256)
void convert_bf16(const float* __restrict__ x, unsigned short* __restrict__ xb) {
  const size_t i = ((size_t)blockIdx.x * 256 + threadIdx.x) * 8;
  float4 f0 = *(const float4*)(x + i);
  float4 f1 = *(const float4*)(x + i + 4);
  ushortv8 u = { f2bf(f0.x), f2bf(f0.y), f2bf(f0.z), f2bf(f0.w),
                 f2bf(f1.x), f2bf(f1.y), f2bf(f1.z), f2bf(f1.w) };
  *(ushortv8*)(xb + i) = u;
}

// ---------------------------------------------------------------------------
// Transpose + fp32->bf16 convert: W[K][N] f32 -> WT[N][K] bf16. 64x64 tiles.
// ---------------------------------------------------------------------------
__global__ __launch_bounds__(256)
void transpose_bf16(const float* __restrict__ W, unsigned short* __restrict__ WT,
                    int K, int N) {
  __shared__ float tile[64][65];
  const int k0 = blockIdx.y * 64, n0 = blockIdx.x * 64;
  const int r = threadIdx.x >> 4, c4 = (threadIdx.x & 15) * 4;
#pragma unroll
  for (int p = 0; p < 4; ++p) {
    int kk = p * 16 + r;
    float4 v = *(const float4*)(W + (size_t)(k0 + kk) * N + n0 + c4);
    tile[kk][c4 + 0] = v.x; tile[kk][c4 + 1] = v.y;
    tile[kk][c4 + 2] = v.z; tile[kk][c4 + 3] = v.w;
  }
  __syncthreads();
#pragma unroll
  for (int p = 0; p < 4; ++p) {
    int nn = p * 16 + r;
    ushort4 o = { f2bf(tile[c4 + 0][nn]), f2bf(tile[c4 + 1][nn]),
                  f2bf(tile[c4 + 2][nn]), f2bf(tile[c4 + 3][nn]) };
    *(ushort4*)(WT + (size_t)(n0 + nn) * K + k0 + c4) = o;
  }
}

// ---------------------------------------------------------------------------
// bf16 MFMA GEMM (validated R3-R10). A bf16 via global_load_lds.
// FUSE_RMSROPE (GEMM1 only, validated R9/R10): for q/k tiles (n0 < 2C),
// apply bias + per-head RMSNorm + RoPE in the epilogue on the f32
// accumulator. R11: NO softmax-scale fold here (flash multiplies by SCL_
// itself, restoring flash's exact R6 instruction sequence -> 84-VGPR alloc).
// ---------------------------------------------------------------------------
template<bool OUT_BF16, bool FUSE_RMSROPE>
__global__ __launch_bounds__(256)
void gemm_mfma(const unsigned short* __restrict__ Ab,
               const unsigned short* __restrict__ Bt,
               const float* __restrict__ bias, void* __restrict__ Cv,
               int K, int lda, int ldb, int ldc) {
  __shared__ unsigned short As[128 * 64];
  __shared__ unsigned short Bs[128 * 64];
  const int tid = threadIdx.x;
  const int l = tid & 63, w = tid >> 6;
  const int m0 = blockIdx.y * 128, n0 = blockIdx.x * 128;
  const int wm = (w & 1) * 64, wn = (w >> 1) * 64;
  const int fr = l & 15, g = l >> 4;

  f32x4 acc[4][4];
#pragma unroll
  for (int i = 0; i < 4; ++i)
#pragma unroll
    for (int j = 0; j < 4; ++j) acc[i][j] = (f32x4)0.f;

  const int gr = l >> 3;
  const int gc = (l & 7) ^ gr;

  for (int kt = 0; kt < K; kt += 64) {
    __syncthreads();
#pragma unroll
    for (int q = 0; q < 4; ++q) {
      int rr = (w * 4 + q) * 8 + gr;
      GLOAD_LDS(Ab + (size_t)(m0 + rr) * lda + kt + gc * 8,
                &As[(w * 4 + q) * 512]);
      GLOAD_LDS(Bt + (size_t)(n0 + rr) * ldb + kt + gc * 8,
                &Bs[(w * 4 + q) * 512]);
    }
    __syncthreads();

#pragma unroll
    for (int s = 0; s < 2; ++s) {
      const int cofs = (((s * 4 + g) ^ (fr & 7)) << 3);
      short8 a[4], b[4];
#pragma unroll
      for (int i = 0; i < 4; ++i)
        a[i] = *(const short8*)&As[(wm + i * 16 + fr) * 64 + cofs];
#pragma unroll
      for (int j = 0; j < 4; ++j)
        b[j] = *(const short8*)&Bs[(wn + j * 16 + fr) * 64 + cofs];
#pragma unroll
      for (int i = 0; i < 4; ++i)
#pragma unroll
        for (int j = 0; j < 4; ++j)
          acc[i][j] = MFMA32(a[i], b[j], acc[i][j]);
    }
  }

  if (FUSE_RMSROPE && n0 < 2 * C_) {
    // ---- fused bias + RMSNorm + RoPE epilogue (q/k tiles) ----
    float bvj[4];
#pragma unroll
    for (int j = 0; j < 4; ++j) bvj[j] = bias[n0 + wn + j * 16 + fr];
#pragma unroll
    for (int i = 0; i < 4; ++i)
#pragma unroll
      for (int j = 0; j < 4; ++j)
#pragma unroll
        for (int rg = 0; rg < 4; ++rg) acc[i][j][rg] += bvj[j];

    float invf[2];
#pragma unroll
    for (int jp = 0; jp < 2; ++jp)
      invf[jp] = __builtin_amdgcn_exp2f(-13.2877123795494f *
                                        (float)(2 * (jp * 16 + fr)) *
                                        (1.0f / 64.0f));
#pragma unroll
    for (int i = 0; i < 4; ++i) {
#pragma unroll
      for (int rg = 0; rg < 4; ++rg) {
        float ss = 0.f;
#pragma unroll
        for (int j = 0; j < 4; ++j) ss += acc[i][j][rg] * acc[i][j][rg];
        ss += __shfl_xor(ss, 1); ss += __shfl_xor(ss, 2);
        ss += __shfl_xor(ss, 4); ss += __shfl_xor(ss, 8);
        const float s = 1.0f / sqrtf(ss * (1.0f / 64.0f) + 1e-6f);
        const int m = m0 + wm + i * 16 + g * 4 + rg;
        const float t = (float)(m & (T_ - 1));
#pragma unroll
        for (int jp = 0; jp < 2; ++jp) {
          float x1 = acc[i][jp][rg] * s;
          float x2 = acc[i][jp + 2][rg] * s;
          float ang = t * invf[jp];
          float cs = __cosf(ang);
          float sn = __sinf(ang);
          acc[i][jp][rg]     = x1 * cs + x2 * sn;
          acc[i][jp + 2][rg] = x2 * cs - x1 * sn;
        }
      }
    }
#pragma unroll
    for (int j = 0; j < 4; ++j) {
      const int n = n0 + wn + j * 16 + fr;
#pragma unroll
      for (int i = 0; i < 4; ++i)
#pragma unroll
        for (int rg = 0; rg < 4; ++rg) {
          const int m = m0 + wm + i * 16 + g * 4 + rg;
          ((unsigned short*)Cv)[(size_t)m * ldc + n] = f2bf(acc[i][j][rg]);
        }
    }
    return;
  }

  // ---- plain epilogue (v tiles of GEMM1, and all of GEMM2) ----
#pragma unroll
  for (int j = 0; j < 4; ++j) {
    const int n = n0 + wn + j * 16 + fr;
    const float bv = bias[n];
#pragma unroll
    for (int i = 0; i < 4; ++i) {
#pragma unroll
      for (int rg = 0; rg < 4; ++rg) {
        const int m = m0 + wm + i * 16 + g * 4 + rg;
        float v = acc[i][j][rg] + bv;
        if (OUT_BF16) ((unsigned short*)Cv)[(size_t)m * ldc + n] = f2bf(v);
        else          ((float*)Cv)[(size_t)m * ldc + n] = v;
      }
    }
  }
}

// ---------------------------------------------------------------------------
// V transpose: bf16 v-columns of qkv -> vT (B,H,D,T) bf16, with lamb applied.
// Also writes the fp32 value output (B,H,T,D) during the load phase.
// Runs BEFORE flash (flash overwrites v-columns with attn output).
// ---------------------------------------------------------------------------
__global__ __launch_bounds__(256)
void vtrans_kernel(const unsigned short* __restrict__ qkv,
                   const float* __restrict__ lambp,
                   unsigned short* __restrict__ vT,
                   float* __restrict__ valOut) {
  __shared__ float tile[64][65];
  const int t0 = blockIdx.x * 64;
  const int head = blockIdx.y;             // b*H + h
  const int b = head >> 4, h = head & 15;
  const float lamb = lambp[0];
  const int r = threadIdx.x >> 4, c4 = (threadIdx.x & 15) * 4;
#pragma unroll
  for (int p = 0; p < 4; ++p) {
    int tt = p * 16 + r;
    ushort4 raw = *(const ushort4*)(
        qkv + (size_t)(b * T_ + t0 + tt) * TC3 + 2 * C_ + h * 64 + c4);
    float4 f;
    f.x = (1.f - lamb) * bf2f(raw.x) + lamb * bf2f(raw.x);
    f.y = (1.f - lamb) * bf2f(raw.y) + lamb * bf2f(raw.y);
    f.z = (1.f - lamb) * bf2f(raw.z) + lamb * bf2f(raw.z);
    f.w = (1.f - lamb) * bf2f(raw.w) + lamb * bf2f(raw.w);
    tile[tt][c4 + 0] = f.x; tile[tt][c4 + 1] = f.y;
    tile[tt][c4 + 2] = f.z; tile[tt][c4 + 3] = f.w;
    *(float4*)(valOut + ((size_t)head * T_ + t0 + tt) * D_ + c4) = f;
  }
  __syncthreads();
#pragma unroll
  for (int p = 0; p < 4; ++p) {
    int d = p * 16 + r;
    ushort4 o = { f2bf(tile[c4 + 0][d]), f2bf(tile[c4 + 1][d]),
                  f2bf(tile[c4 + 2][d]), f2bf(tile[c4 + 3][d]) };
    *(ushort4*)(vT + ((size_t)head * D_ + d) * T_ + t0 + c4) = o;
  }
}

// ---------------------------------------------------------------------------
// MFMA flash attention — v15 = EXACT R6 body (validated 90.6us @ 84 VGPR)
// + __launch_bounds__(256,6).
// R10 post-mortem: waves-per-eu=6 request alone did NOT move VGPR (stayed
// 100) — the allocator wouldn't find an 85-reg schedule for the fold-less
// sequence. But R6 PROVED the 84-reg allocation exists for the sequence
// WITH the SCL_ multiply. So: un-fold QSCL from gemm, restore arg*SCL_
// here — byte-identical R6 instruction stream — and keep the bound as a
// steer. (Rule #19: allocation is schedule-dependent; give the allocator
// the input it already solved.)
// ---------------------------------------------------------------------------
#define SCL_ (0.125f * 1.44269504088896f)   // 1/sqrt(D) * log2(e)

__device__ __forceinline__ void attn_tile(
    const unsigned short* Ks,
    const unsigned short* Vs,
    const short8 (&qf)[2][2], int qrow0 /* q0 + w*32 */, int k0,
    int fr, int quad, int f8,
    float (&l_pt)[2], f32x4 (&o)[2][4]) {
  // ---- S^T = K Q^T : C/D col = q(fr), row = key(quad*4+reg) ----
  f32x4 st[2][4];
#pragma unroll
  for (int i = 0; i < 2; ++i)
#pragma unroll
    for (int j = 0; j < 4; ++j) st[i][j] = (f32x4)0.f;

  __builtin_amdgcn_s_setprio(1);
#pragma unroll
  for (int kc = 0; kc < 2; ++kc) {
    const int cofs = (((kc * 4 + quad) ^ f8) << 3);
#pragma unroll
    for (int j = 0; j < 4; ++j) {
      short8 kf = *(const short8*)&Ks[(j * 16 + fr) * 64 + cofs];
      st[0][j] = MFMA32(kf, qf[kc][0], st[0][j]);
      st[1][j] = MFMA32(kf, qf[kc][1], st[1][j]);
    }
  }
  __builtin_amdgcn_s_setprio(0);

  // ---- softmax (fixed basis, per-lane) + pack P into A-frags ----
  short4b pa[2][4];
#pragma unroll
  for (int i = 0; i < 2; ++i) {
    const int qg = qrow0 + i * 16 + fr;
#pragma unroll
    for (int j = 0; j < 4; ++j) {
      const int kg = k0 + j * 16 + quad * 4;
#pragma unroll
      for (int r = 0; r < 4; ++r) {
        float arg = st[i][j][r] * SCL_;
        if (kg + r > qg) arg = -INFINITY;   // branchless causal mask
        float p = __builtin_amdgcn_exp2f(arg);
        l_pt[i] += p;
        st[i][j][r] = p;
      }
      bf16x4 pb = { (__bf16)st[i][j][0], (__bf16)st[i][j][1],
                    (__bf16)st[i][j][2], (__bf16)st[i][j][3] };
      pa[i][j] = __builtin_bit_cast(short4b, pb);
    }
  }

  // ---- O^T += P V via 16x16x16 MFMA (P in regs, V^T b64 B-frags) ----
  __builtin_amdgcn_s_setprio(1);
#pragma unroll
  for (int c = 0; c < 4; ++c) {
    const int vofs = ((((c * 2 + (quad >> 1)) ^ f8) << 3) + (quad & 1) * 4);
#pragma unroll
    for (int jd = 0; jd < 4; ++jd) {
      short4b vf = *(const short4b*)&Vs[(jd * 16 + fr) * 64 + vofs];
      o[0][jd] = MFMA16(pa[0][c], vf, o[0][jd]);
      o[1][jd] = MFMA16(pa[1][c], vf, o[1][jd]);
    }
  }
  __builtin_amdgcn_s_setprio(0);
}

__device__ __forceinline__ void attn_store(
    unsigned short* __restrict__ qkv, int bT, int h, int qrow0,
    int fr, int quad, float (&l_pt)[2], f32x4 (&o)[2][4]) {
#pragma unroll
  for (int i = 0; i < 2; ++i) {
    float lv = l_pt[i];
    lv += __shfl_xor(lv, 16);
    lv += __shfl_xor(lv, 32);
    float inv = 1.0f / lv;
    float invq[4];
#pragma unroll
    for (int r = 0; r < 4; ++r) invq[r] = __shfl(inv, quad * 4 + r);
#pragma unroll
    for (int jd = 0; jd < 4; ++jd) {
      const int d = jd * 16 + fr;
#pragma unroll
      for (int r = 0; r < 4; ++r) {
        const int row = qrow0 + i * 16 + quad * 4 + r;
        qkv[(size_t)(bT + row) * TC3 + 2 * C_ + h * 64 + d] =
            f2bf(o[i][jd][r] * invq[r]);
      }
    }
  }
}

__global__ __launch_bounds__(256, 6)
void flash_mfma(unsigned short* __restrict__ qkv,
                const unsigned short* __restrict__ vT) {
  __shared__ unsigned short KV[2][2][64 * 64];   // [buf][K=0 / V=1], 32 KB
  // Q (128x64 = 16KB) overlays KV[0] during the prologue only.

  // balanced work mapping: qts {x, 15-x, (x+8)&15, 15-((x+8)&15)} per CU
  const int z = blockIdx.z;
  const int xx = ((int)blockIdx.x + ((z >> 1) << 3)) & 15;
  const int qt = (z & 1) ? (15 - xx) : xx;
  const int b  = z;
  const int h  = blockIdx.y;
  const int bT = b * T_;

  const int tid = threadIdx.x;
  const int w = tid >> 6, l = tid & 63;
  const int fr = l & 15, quad = l >> 4;
  const int q0 = qt * 128;
  const int gr = l >> 3;
  const int gc = (l & 7) ^ gr;
  const int f8 = fr & 7;

#define STAGE(KS, VS, KT) do { \
  const int _k0 = (KT) * 64; \
  _Pragma("unroll") \
  for (int s_ = 0; s_ < 2; ++s_) { \
    int row_ = w * 16 + s_ * 8; \
    GLOAD_LDS(qkv + (size_t)(bT + _k0 + row_ + gr) * TC3 + C_ + h * 64 + gc * 8, \
              &(KS)[row_ * 64]); \
    GLOAD_LDS(vT + ((size_t)(b * H_ + h) * D_ + row_ + gr) * T_ + _k0 + gc * 8, \
              &(VS)[row_ * 64]); \
  } \
} while (0)

  // ---- prologue: Q into KV[0] (linear 8192 shorts), tile0 into KV[1] ----
  unsigned short* Qb = &KV[0][0][0];
#pragma unroll
  for (int s = 0; s < 4; ++s) {
    int rbase = w * 32 + s * 8;   // wave-uniform
    GLOAD_LDS(qkv + (size_t)(bT + q0 + rbase + gr) * TC3 + h * 64 + gc * 8,
              Qb + rbase * 64);
  }
  STAGE(KV[1][0], KV[1][1], 0);
  __syncthreads();   // full drain: Q + tile0 staged

  // hoist iteration-invariant Q fragments (B-operand of S^T MFMA)
  short8 qf[2][2];
#pragma unroll
  for (int kc = 0; kc < 2; ++kc) {
    const int cofs = (((kc * 4 + quad) ^ f8) << 3);
    qf[kc][0] = *(const short8*)&Qb[(w * 32 + fr) * 64 + cofs];
    qf[kc][1] = *(const short8*)&Qb[(w * 32 + 16 + fr) * 64 + cofs];
  }
  __syncthreads();   // all waves done reading Q; KV[0] free for staging

  float l_pt[2] = {0.f, 0.f};
  f32x4 o[2][4];
#pragma unroll
  for (int i = 0; i < 2; ++i)
#pragma unroll
    for (int j = 0; j < 4; ++j) o[i][j] = (f32x4)0.f;

  const int nk = 2 * qt + 2;
  const int qr0 = q0 + w * 32;

  int cur = 1;   // tile0 lives in KV[1]
  for (int kt = 0; kt < nk; ++kt) {
    const int nxt = cur ^ 1;
    if (kt + 1 < nk) {
      STAGE(KV[nxt][0], KV[nxt][1], kt + 1);
      asm volatile("s_waitcnt vmcnt(4)" ::: "memory");   // current tile landed
    } else {
      asm volatile("s_waitcnt vmcnt(0)" ::: "memory");   // last tile: drain
    }
    __builtin_amdgcn_s_barrier();
    asm volatile("" ::: "memory");

    attn_tile(&KV[cur][0][0], &KV[cur][1][0], qf, qr0, kt * 64,
              fr, quad, f8, l_pt, o);

    if (kt + 1 < nk) {           // WAR fence: readers done before next STAGE
      __builtin_amdgcn_s_barrier();
      asm volatile("" ::: "memory");
    }
    cur = nxt;
  }

  // ---- epilogue: reduce l over quads, store O/l (row=q via quad*4+r) ----
  attn_store(qkv, bT, h, qr0, fr, quad, l_pt, o);
#undef STAGE
}

// ---------------------------------------------------------------------------
// Launch. d_in: x, Wqkv, bqkv, Wproj, bproj, lamb.
// d_out: out (B*T*C f32) then value (B*H*T*D f32).
// ws: qkvb 50.3MB | WqkvT 6.3MB | WprojT 2.1MB | vT 16.8MB | xb 16.8MB.
// rmsrope fused into GEMM1's epilogue (R9, validated).
// ---------------------------------------------------------------------------
extern "C" void kernel_launch(void* const* d_in, const int* in_sizes, int n_in,
                              void* d_out, int out_size, void* d_ws, size_t ws_size,
                              hipStream_t stream) {
  const float* x     = (const float*)d_in[0];
  const float* Wqkv  = (const float*)d_in[1];
  const float* bqkv  = (const float*)d_in[2];
  const float* Wproj = (const float*)d_in[3];
  const float* bproj = (const float*)d_in[4];
  const float* lamb  = (const float*)d_in[5];

  float* out     = (float*)d_out;
  float* val_out = out + (size_t)B_ * T_ * C_;

  unsigned short* qkvb   = (unsigned short*)d_ws;                 // B*T*3C
  unsigned short* WqkvT  = qkvb + (size_t)B_ * T_ * TC3;          // 3C x C
  unsigned short* WprojT = WqkvT + (size_t)TC3 * C_;              // C x C
  unsigned short* vT     = WprojT + (size_t)C_ * C_;              // B*H*D*T
  unsigned short* xb     = vT + (size_t)B_ * H_ * D_ * T_;        // B*T*C

  convert_bf16<<<dim3((B_ * T_ * C_) / 2048), 256, 0, stream>>>(x, xb);
  transpose_bf16<<<dim3(TC3 / 64, C_ / 64), 256, 0, stream>>>(Wqkv, WqkvT, C_, TC3);
  transpose_bf16<<<dim3(C_ / 64, C_ / 64), 256, 0, stream>>>(Wproj, WprojT, C_, C_);

  gemm_mfma<true, true><<<dim3(TC3 / 128, (B_ * T_) / 128), 256, 0, stream>>>(
      xb, WqkvT, bqkv, qkvb, C_, C_, C_, TC3);

  vtrans_kernel<<<dim3(T_ / 64, B_ * H_), 256, 0, stream>>>(qkvb, lamb, vT, val_out);

  flash_mfma<<<dim3(16, H_, B_), 256, 0, stream>>>(qkvb, vT);

  gemm_mfma<false, false><<<dim3(C_ / 128, (B_ * T_) / 128), 256, 0, stream>>>(
      qkvb + 2 * C_, WprojT, bproj, out, C_, TC3, C_, C_);
}

// Round 12
// 291.295 us; speedup vs baseline: 1.1243x; 1.0296x over previous
//
#include <hip/hip_runtime.h>
#include <math.h>

// Problem constants (B,T,C,H) = (4, 2048, 1024, 16), D = 64.
#define B_   4
#define T_   2048
#define C_   1024
#define H_   16
#define D_   64
#define TC3  3072   // 3*C

typedef __attribute__((ext_vector_type(8))) short short8;
typedef __attribute__((ext_vector_type(4))) short short4b;
typedef __attribute__((ext_vector_type(8))) unsigned short ushortv8;
typedef __attribute__((ext_vector_type(4))) float f32x4;
typedef __attribute__((ext_vector_type(4))) __bf16 bf16x4;

__device__ __forceinline__ float bf2f(unsigned short u) {
  unsigned int x = ((unsigned int)u) << 16;
  float f; __builtin_memcpy(&f, &x, 4); return f;
}
__device__ __forceinline__ unsigned short f2bf(float f) {   // round-nearest-even
  unsigned int x; __builtin_memcpy(&x, &f, 4);
  x += 0x7fff + ((x >> 16) & 1);
  return (unsigned short)(x >> 16);
}

#define MFMA32(a, b, c) __builtin_amdgcn_mfma_f32_16x16x32_bf16(a, b, c, 0, 0, 0)
#if __has_builtin(__builtin_amdgcn_mfma_f32_16x16x16_bf16)
#define MFMA16(a, b, c) __builtin_amdgcn_mfma_f32_16x16x16_bf16(a, b, c, 0, 0, 0)
#else
#define MFMA16(a, b, c) __builtin_amdgcn_mfma_f32_16x16x16bf16_1k(a, b, c, 0, 0, 0)
#endif

#define GLOAD_LDS(gp, lp) __builtin_amdgcn_global_load_lds( \
    (const __attribute__((address_space(1))) unsigned int*)(gp), \
    (__attribute__((address_space(3))) unsigned int*)(lp), 16, 0, 0)

// ---------------------------------------------------------------------------
// x f32 -> bf16 (lets GEMM1 use the pure-bf16 global_load_lds staging path).
// ---------------------------------------------------------------------------
__global__ __launch_bounds__(256)
void convert_bf16(const float* __restrict__ x, unsigned short* __restrict__ xb) {
  const size_t i = ((size_t)blockIdx.x * 256 + threadIdx.x) * 8;
  float4 f0 = *(const float4*)(x + i);
  float4 f1 = *(const float4*)(x + i + 4);
  ushortv8 u = { f2bf(f0.x), f2bf(f0.y), f2bf(f0.z), f2bf(f0.w),
                 f2bf(f1.x), f2bf(f1.y), f2bf(f1.z), f2bf(f1.w) };
  *(ushortv8*)(xb + i) = u;
}

// ---------------------------------------------------------------------------
// Transpose + fp32->bf16 convert: W[K][N] f32 -> WT[N][K] bf16. 64x64 tiles.
// ---------------------------------------------------------------------------
__global__ __launch_bounds__(256)
void transpose_bf16(const float* __restrict__ W, unsigned short* __restrict__ WT,
                    int K, int N) {
  __shared__ float tile[64][65];
  const int k0 = blockIdx.y * 64, n0 = blockIdx.x * 64;
  const int r = threadIdx.x >> 4, c4 = (threadIdx.x & 15) * 4;
#pragma unroll
  for (int p = 0; p < 4; ++p) {
    int kk = p * 16 + r;
    float4 v = *(const float4*)(W + (size_t)(k0 + kk) * N + n0 + c4);
    tile[kk][c4 + 0] = v.x; tile[kk][c4 + 1] = v.y;
    tile[kk][c4 + 2] = v.z; tile[kk][c4 + 3] = v.w;
  }
  __syncthreads();
#pragma unroll
  for (int p = 0; p < 4; ++p) {
    int nn = p * 16 + r;
    ushort4 o = { f2bf(tile[c4 + 0][nn]), f2bf(tile[c4 + 1][nn]),
                  f2bf(tile[c4 + 2][nn]), f2bf(tile[c4 + 3][nn]) };
    *(ushort4*)(WT + (size_t)(n0 + nn) * K + k0 + c4) = o;
  }
}

// ---------------------------------------------------------------------------
// bf16 MFMA GEMM (validated R3-R11). A bf16 via global_load_lds.
// FUSE_QKV (GEMM1 only):
//  * q/k tiles (n0 < 2C): bias + per-head RMSNorm + RoPE on the f32 acc
//    (validated R9-R11; no QSCL fold — flash applies SCL_ itself, R11).
//  * v tiles (n0 >= 2C), NEW R12: bias + lamb, then write valOut f32
//    DIRECTLY (tighter than the old bf16 round-trip) and vT bf16 via an
//    in-LDS transpose (As/Bs region aliased as a padded [128][65] tile,
//    two passes = two heads). qkvb v-columns are NOT written — nothing
//    reads them before flash overwrites them with attn output. This
//    replaces the standalone vtrans kernel (launch + 16.8MB read +
//    16.8MB qkvb write eliminated).
// ---------------------------------------------------------------------------
template<bool OUT_BF16, bool FUSE_QKV>
__global__ __launch_bounds__(256)
void gemm_mfma(const unsigned short* __restrict__ Ab,
               const unsigned short* __restrict__ Bt,
               const float* __restrict__ bias, void* __restrict__ Cv,
               int K, int lda, int ldb, int ldc,
               const float* __restrict__ lambp,
               unsigned short* __restrict__ vT,
               float* __restrict__ valOut) {
  __shared__ unsigned short SH[2 * 128 * 64];   // As | Bs (aliased by v-epilogue)
  unsigned short* As = SH;
  unsigned short* Bs = SH + 128 * 64;
  const int tid = threadIdx.x;
  const int l = tid & 63, w = tid >> 6;
  const int m0 = blockIdx.y * 128, n0 = blockIdx.x * 128;
  const int wm = (w & 1) * 64, wn = (w >> 1) * 64;
  const int fr = l & 15, g = l >> 4;

  f32x4 acc[4][4];
#pragma unroll
  for (int i = 0; i < 4; ++i)
#pragma unroll
    for (int j = 0; j < 4; ++j) acc[i][j] = (f32x4)0.f;

  const int gr = l >> 3;
  const int gc = (l & 7) ^ gr;

  for (int kt = 0; kt < K; kt += 64) {
    __syncthreads();
#pragma unroll
    for (int q = 0; q < 4; ++q) {
      int rr = (w * 4 + q) * 8 + gr;
      GLOAD_LDS(Ab + (size_t)(m0 + rr) * lda + kt + gc * 8,
                &As[(w * 4 + q) * 512]);
      GLOAD_LDS(Bt + (size_t)(n0 + rr) * ldb + kt + gc * 8,
                &Bs[(w * 4 + q) * 512]);
    }
    __syncthreads();

#pragma unroll
    for (int s = 0; s < 2; ++s) {
      const int cofs = (((s * 4 + g) ^ (fr & 7)) << 3);
      short8 a[4], b[4];
#pragma unroll
      for (int i = 0; i < 4; ++i)
        a[i] = *(const short8*)&As[(wm + i * 16 + fr) * 64 + cofs];
#pragma unroll
      for (int j = 0; j < 4; ++j)
        b[j] = *(const short8*)&Bs[(wn + j * 16 + fr) * 64 + cofs];
#pragma unroll
      for (int i = 0; i < 4; ++i)
#pragma unroll
        for (int j = 0; j < 4; ++j)
          acc[i][j] = MFMA32(a[i], b[j], acc[i][j]);
    }
  }

  if (FUSE_QKV && n0 < 2 * C_) {
    // ---- fused bias + RMSNorm + RoPE epilogue (q/k tiles) ----
    float bvj[4];
#pragma unroll
    for (int j = 0; j < 4; ++j) bvj[j] = bias[n0 + wn + j * 16 + fr];
#pragma unroll
    for (int i = 0; i < 4; ++i)
#pragma unroll
      for (int j = 0; j < 4; ++j)
#pragma unroll
        for (int rg = 0; rg < 4; ++rg) acc[i][j][rg] += bvj[j];

    float invf[2];
#pragma unroll
    for (int jp = 0; jp < 2; ++jp)
      invf[jp] = __builtin_amdgcn_exp2f(-13.2877123795494f *
                                        (float)(2 * (jp * 16 + fr)) *
                                        (1.0f / 64.0f));
#pragma unroll
    for (int i = 0; i < 4; ++i) {
#pragma unroll
      for (int rg = 0; rg < 4; ++rg) {
        float ss = 0.f;
#pragma unroll
        for (int j = 0; j < 4; ++j) ss += acc[i][j][rg] * acc[i][j][rg];
        ss += __shfl_xor(ss, 1); ss += __shfl_xor(ss, 2);
        ss += __shfl_xor(ss, 4); ss += __shfl_xor(ss, 8);
        const float s = 1.0f / sqrtf(ss * (1.0f / 64.0f) + 1e-6f);
        const int m = m0 + wm + i * 16 + g * 4 + rg;
        const float t = (float)(m & (T_ - 1));
#pragma unroll
        for (int jp = 0; jp < 2; ++jp) {
          float x1 = acc[i][jp][rg] * s;
          float x2 = acc[i][jp + 2][rg] * s;
          float ang = t * invf[jp];
          float cs = __cosf(ang);
          float sn = __sinf(ang);
          acc[i][jp][rg]     = x1 * cs + x2 * sn;
          acc[i][jp + 2][rg] = x2 * cs - x1 * sn;
        }
      }
    }
#pragma unroll
    for (int j = 0; j < 4; ++j) {
      const int n = n0 + wn + j * 16 + fr;
#pragma unroll
      for (int i = 0; i < 4; ++i)
#pragma unroll
        for (int rg = 0; rg < 4; ++rg) {
          const int m = m0 + wm + i * 16 + g * 4 + rg;
          ((unsigned short*)Cv)[(size_t)m * ldc + n] = f2bf(acc[i][j][rg]);
        }
    }
    return;
  }

  if (FUSE_QKV) {
    // ---- fused V epilogue (n0 >= 2C): bias + lamb -> valOut f32 + vT bf16 ----
    const float lamb = lambp[0];
    const int bb  = m0 >> 11;            // T_ = 2048; block spans one b
    const int t0b = m0 & (T_ - 1);       // block-local t base
    const int h0  = (n0 - 2 * C_) >> 6;  // 2 heads per 128-wide tile
    const int hh  = h0 + (wn >> 6);      // this wave's head (j*16+fr < 64)
    float bvj[4];
#pragma unroll
    for (int j = 0; j < 4; ++j) bvj[j] = bias[n0 + wn + j * 16 + fr];
#pragma unroll
    for (int i = 0; i < 4; ++i)
#pragma unroll
      for (int j = 0; j < 4; ++j)
#pragma unroll
        for (int rg = 0; rg < 4; ++rg) {
          float v = acc[i][j][rg] + bvj[j];
          acc[i][j][rg] = (1.f - lamb) * v + lamb * v;
        }

    // valOut (B,H,T,D) f32 — 16 consecutive d per 16-lane group
    const size_t vob = (size_t)(bb * H_ + hh) * T_;
#pragma unroll
    for (int i = 0; i < 4; ++i)
#pragma unroll
      for (int rg = 0; rg < 4; ++rg) {
        const int t = t0b + wm + i * 16 + g * 4 + rg;
#pragma unroll
        for (int j = 0; j < 4; ++j)
          valOut[(vob + t) * D_ + j * 16 + fr] = acc[i][j][rg];
      }

    // vT (B,H,D,T) bf16 via LDS transpose; two passes (one per head).
    unsigned short (*tile)[65] = (unsigned short (*)[65])SH;  // 128x65 = 16.6KB
#pragma unroll
    for (int hp = 0; hp < 2; ++hp) {
      __syncthreads();                    // As/Bs reads (or prev pass) done
      if ((wn >> 6) == hp) {
#pragma unroll
        for (int i = 0; i < 4; ++i)
#pragma unroll
          for (int j = 0; j < 4; ++j)
#pragma unroll
            for (int rg = 0; rg < 4; ++rg)
              tile[wm + i * 16 + g * 4 + rg][j * 16 + fr] =
                  f2bf(acc[i][j][rg]);
      }
      __syncthreads();
      // 256 threads: d = tid>>2 (0..63), t-chunk = (tid&3)*32 (32 shorts each)
      const int d  = tid >> 2;
      const int tc = (tid & 3) * 32;
      unsigned short* dst =
          vT + ((size_t)(bb * H_ + h0 + hp) * D_ + d) * T_ + t0b + tc;
#pragma unroll
      for (int c8 = 0; c8 < 4; ++c8) {
        ushortv8 o8;
#pragma unroll
        for (int e = 0; e < 8; ++e) o8[e] = tile[tc + c8 * 8 + e][d];
        *(ushortv8*)(dst + c8 * 8) = o8;
      }
    }
    return;
  }

  // ---- plain epilogue (GEMM2) ----
#pragma unroll
  for (int j = 0; j < 4; ++j) {
    const int n = n0 + wn + j * 16 + fr;
    const float bv = bias[n];
#pragma unroll
    for (int i = 0; i < 4; ++i) {
#pragma unroll
      for (int rg = 0; rg < 4; ++rg) {
        const int m = m0 + wm + i * 16 + g * 4 + rg;
        float v = acc[i][j][rg] + bv;
        if (OUT_BF16) ((unsigned short*)Cv)[(size_t)m * ldc + n] = f2bf(v);
        else          ((float*)Cv)[(size_t)m * ldc + n] = v;
      }
    }
  }
}

// ---------------------------------------------------------------------------
// V transpose kernel — NO LONGER LAUNCHED (fused into GEMM1's v epilogue,
// R12). Definition kept to minimize TU/regalloc perturbation of flash
// (rule #19: R9 showed unrelated TU edits flip flash's VGPR allocation).
// ---------------------------------------------------------------------------
__global__ __launch_bounds__(256)
void vtrans_kernel(const unsigned short* __restrict__ qkv,
                   const float* __restrict__ lambp,
                   unsigned short* __restrict__ vT,
                   float* __restrict__ valOut) {
  __shared__ float tile[64][65];
  const int t0 = blockIdx.x * 64;
  const int head = blockIdx.y;             // b*H + h
  const int b = head >> 4, h = head & 15;
  const float lamb = lambp[0];
  const int r = threadIdx.x >> 4, c4 = (threadIdx.x & 15) * 4;
#pragma unroll
  for (int p = 0; p < 4; ++p) {
    int tt = p * 16 + r;
    ushort4 raw = *(const ushort4*)(
        qkv + (size_t)(b * T_ + t0 + tt) * TC3 + 2 * C_ + h * 64 + c4);
    float4 f;
    f.x = (1.f - lamb) * bf2f(raw.x) + lamb * bf2f(raw.x);
    f.y = (1.f - lamb) * bf2f(raw.y) + lamb * bf2f(raw.y);
    f.z = (1.f - lamb) * bf2f(raw.z) + lamb * bf2f(raw.z);
    f.w = (1.f - lamb) * bf2f(raw.w) + lamb * bf2f(raw.w);
    tile[tt][c4 + 0] = f.x; tile[tt][c4 + 1] = f.y;
    tile[tt][c4 + 2] = f.z; tile[tt][c4 + 3] = f.w;
    *(float4*)(valOut + ((size_t)head * T_ + t0 + tt) * D_ + c4) = f;
  }
  __syncthreads();
#pragma unroll
  for (int p = 0; p < 4; ++p) {
    int d = p * 16 + r;
    ushort4 o = { f2bf(tile[c4 + 0][d]), f2bf(tile[c4 + 1][d]),
                  f2bf(tile[c4 + 2][d]), f2bf(tile[c4 + 3][d]) };
    *(ushort4*)(vT + ((size_t)head * D_ + d) * T_ + t0 + c4) = o;
  }
}

// ---------------------------------------------------------------------------
// MFMA flash attention — v15 (R11, validated 90.6us @ 84 VGPR): EXACT R6
// body + __launch_bounds__(256,6). SOURCE FROZEN — do not touch (rule #19;
// flash dur tracks its VGPR allocation, which is schedule-input-dependent).
// ---------------------------------------------------------------------------
#define SCL_ (0.125f * 1.44269504088896f)   // 1/sqrt(D) * log2(e)

__device__ __forceinline__ void attn_tile(
    const unsigned short* Ks,
    const unsigned short* Vs,
    const short8 (&qf)[2][2], int qrow0 /* q0 + w*32 */, int k0,
    int fr, int quad, int f8,
    float (&l_pt)[2], f32x4 (&o)[2][4]) {
  // ---- S^T = K Q^T : C/D col = q(fr), row = key(quad*4+reg) ----
  f32x4 st[2][4];
#pragma unroll
  for (int i = 0; i < 2; ++i)
#pragma unroll
    for (int j = 0; j < 4; ++j) st[i][j] = (f32x4)0.f;

  __builtin_amdgcn_s_setprio(1);
#pragma unroll
  for (int kc = 0; kc < 2; ++kc) {
    const int cofs = (((kc * 4 + quad) ^ f8) << 3);
#pragma unroll
    for (int j = 0; j < 4; ++j) {
      short8 kf = *(const short8*)&Ks[(j * 16 + fr) * 64 + cofs];
      st[0][j] = MFMA32(kf, qf[kc][0], st[0][j]);
      st[1][j] = MFMA32(kf, qf[kc][1], st[1][j]);
    }
  }
  __builtin_amdgcn_s_setprio(0);

  // ---- softmax (fixed basis, per-lane) + pack P into A-frags ----
  short4b pa[2][4];
#pragma unroll
  for (int i = 0; i < 2; ++i) {
    const int qg = qrow0 + i * 16 + fr;
#pragma unroll
    for (int j = 0; j < 4; ++j) {
      const int kg = k0 + j * 16 + quad * 4;
#pragma unroll
      for (int r = 0; r < 4; ++r) {
        float arg = st[i][j][r] * SCL_;
        if (kg + r > qg) arg = -INFINITY;   // branchless causal mask
        float p = __builtin_amdgcn_exp2f(arg);
        l_pt[i] += p;
        st[i][j][r] = p;
      }
      bf16x4 pb = { (__bf16)st[i][j][0], (__bf16)st[i][j][1],
                    (__bf16)st[i][j][2], (__bf16)st[i][j][3] };
      pa[i][j] = __builtin_bit_cast(short4b, pb);
    }
  }

  // ---- O^T += P V via 16x16x16 MFMA (P in regs, V^T b64 B-frags) ----
  __builtin_amdgcn_s_setprio(1);
#pragma unroll
  for (int c = 0; c < 4; ++c) {
    const int vofs = ((((c * 2 + (quad >> 1)) ^ f8) << 3) + (quad & 1) * 4);
#pragma unroll
    for (int jd = 0; jd < 4; ++jd) {
      short4b vf = *(const short4b*)&Vs[(jd * 16 + fr) * 64 + vofs];
      o[0][jd] = MFMA16(pa[0][c], vf, o[0][jd]);
      o[1][jd] = MFMA16(pa[1][c], vf, o[1][jd]);
    }
  }
  __builtin_amdgcn_s_setprio(0);
}

__device__ __forceinline__ void attn_store(
    unsigned short* __restrict__ qkv, int bT, int h, int qrow0,
    int fr, int quad, float (&l_pt)[2], f32x4 (&o)[2][4]) {
#pragma unroll
  for (int i = 0; i < 2; ++i) {
    float lv = l_pt[i];
    lv += __shfl_xor(lv, 16);
    lv += __shfl_xor(lv, 32);
    float inv = 1.0f / lv;
    float invq[4];
#pragma unroll
    for (int r = 0; r < 4; ++r) invq[r] = __shfl(inv, quad * 4 + r);
#pragma unroll
    for (int jd = 0; jd < 4; ++jd) {
      const int d = jd * 16 + fr;
#pragma unroll
      for (int r = 0; r < 4; ++r) {
        const int row = qrow0 + i * 16 + quad * 4 + r;
        qkv[(size_t)(bT + row) * TC3 + 2 * C_ + h * 64 + d] =
            f2bf(o[i][jd][r] * invq[r]);
      }
    }
  }
}

__global__ __launch_bounds__(256, 6)
void flash_mfma(unsigned short* __restrict__ qkv,
                const unsigned short* __restrict__ vT) {
  __shared__ unsigned short KV[2][2][64 * 64];   // [buf][K=0 / V=1], 32 KB
  // Q (128x64 = 16KB) overlays KV[0] during the prologue only.

  // balanced work mapping: qts {x, 15-x, (x+8)&15, 15-((x+8)&15)} per CU
  const int z = blockIdx.z;
  const int xx = ((int)blockIdx.x + ((z >> 1) << 3)) & 15;
  const int qt = (z & 1) ? (15 - xx) : xx;
  const int b  = z;
  const int h  = blockIdx.y;
  const int bT = b * T_;

  const int tid = threadIdx.x;
  const int w = tid >> 6, l = tid & 63;
  const int fr = l & 15, quad = l >> 4;
  const int q0 = qt * 128;
  const int gr = l >> 3;
  const int gc = (l & 7) ^ gr;
  const int f8 = fr & 7;

#define STAGE(KS, VS, KT) do { \
  const int _k0 = (KT) * 64; \
  _Pragma("unroll") \
  for (int s_ = 0; s_ < 2; ++s_) { \
    int row_ = w * 16 + s_ * 8; \
    GLOAD_LDS(qkv + (size_t)(bT + _k0 + row_ + gr) * TC3 + C_ + h * 64 + gc * 8, \
              &(KS)[row_ * 64]); \
    GLOAD_LDS(vT + ((size_t)(b * H_ + h) * D_ + row_ + gr) * T_ + _k0 + gc * 8, \
              &(VS)[row_ * 64]); \
  } \
} while (0)

  // ---- prologue: Q into KV[0] (linear 8192 shorts), tile0 into KV[1] ----
  unsigned short* Qb = &KV[0][0][0];
#pragma unroll
  for (int s = 0; s < 4; ++s) {
    int rbase = w * 32 + s * 8;   // wave-uniform
    GLOAD_LDS(qkv + (size_t)(bT + q0 + rbase + gr) * TC3 + h * 64 + gc * 8,
              Qb + rbase * 64);
  }
  STAGE(KV[1][0], KV[1][1], 0);
  __syncthreads();   // full drain: Q + tile0 staged

  // hoist iteration-invariant Q fragments (B-operand of S^T MFMA)
  short8 qf[2][2];
#pragma unroll
  for (int kc = 0; kc < 2; ++kc) {
    const int cofs = (((kc * 4 + quad) ^ f8) << 3);
    qf[kc][0] = *(const short8*)&Qb[(w * 32 + fr) * 64 + cofs];
    qf[kc][1] = *(const short8*)&Qb[(w * 32 + 16 + fr) * 64 + cofs];
  }
  __syncthreads();   // all waves done reading Q; KV[0] free for staging

  float l_pt[2] = {0.f, 0.f};
  f32x4 o[2][4];
#pragma unroll
  for (int i = 0; i < 2; ++i)
#pragma unroll
    for (int j = 0; j < 4; ++j) o[i][j] = (f32x4)0.f;

  const int nk = 2 * qt + 2;
  const int qr0 = q0 + w * 32;

  int cur = 1;   // tile0 lives in KV[1]
  for (int kt = 0; kt < nk; ++kt) {
    const int nxt = cur ^ 1;
    if (kt + 1 < nk) {
      STAGE(KV[nxt][0], KV[nxt][1], kt + 1);
      asm volatile("s_waitcnt vmcnt(4)" ::: "memory");   // current tile landed
    } else {
      asm volatile("s_waitcnt vmcnt(0)" ::: "memory");   // last tile: drain
    }
    __builtin_amdgcn_s_barrier();
    asm volatile("" ::: "memory");

    attn_tile(&KV[cur][0][0], &KV[cur][1][0], qf, qr0, kt * 64,
              fr, quad, f8, l_pt, o);

    if (kt + 1 < nk) {           // WAR fence: readers done before next STAGE
      __builtin_amdgcn_s_barrier();
      asm volatile("" ::: "memory");
    }
    cur = nxt;
  }

  // ---- epilogue: reduce l over quads, store O/l (row=q via quad*4+r) ----
  attn_store(qkv, bT, h, qr0, fr, quad, l_pt, o);
#undef STAGE
}

// ---------------------------------------------------------------------------
// Launch. d_in: x, Wqkv, bqkv, Wproj, bproj, lamb.
// d_out: out (B*T*C f32) then value (B*H*T*D f32).
// ws: qkvb 50.3MB | WqkvT 6.3MB | WprojT 2.1MB | vT 16.8MB | xb 16.8MB.
// R12: vtrans fused into GEMM1's v epilogue (valOut f32 direct + vT via
// LDS transpose; qkvb v-columns never written pre-flash).
// ---------------------------------------------------------------------------
extern "C" void kernel_launch(void* const* d_in, const int* in_sizes, int n_in,
                              void* d_out, int out_size, void* d_ws, size_t ws_size,
                              hipStream_t stream) {
  const float* x     = (const float*)d_in[0];
  const float* Wqkv  = (const float*)d_in[1];
  const float* bqkv  = (const float*)d_in[2];
  const float* Wproj = (const float*)d_in[3];
  const float* bproj = (const float*)d_in[4];
  const float* lamb  = (const float*)d_in[5];

  float* out     = (float*)d_out;
  float* val_out = out + (size_t)B_ * T_ * C_;

  unsigned short* qkvb   = (unsigned short*)d_ws;                 // B*T*3C
  unsigned short* WqkvT  = qkvb + (size_t)B_ * T_ * TC3;          // 3C x C
  unsigned short* WprojT = WqkvT + (size_t)TC3 * C_;              // C x C
  unsigned short* vT     = WprojT + (size_t)C_ * C_;              // B*H*D*T
  unsigned short* xb     = vT + (size_t)B_ * H_ * D_ * T_;        // B*T*C

  convert_bf16<<<dim3((B_ * T_ * C_) / 2048), 256, 0, stream>>>(x, xb);
  transpose_bf16<<<dim3(TC3 / 64, C_ / 64), 256, 0, stream>>>(Wqkv, WqkvT, C_, TC3);
  transpose_bf16<<<dim3(C_ / 64, C_ / 64), 256, 0, stream>>>(Wproj, WprojT, C_, C_);

  gemm_mfma<true, true><<<dim3(TC3 / 128, (B_ * T_) / 128), 256, 0, stream>>>(
      xb, WqkvT, bqkv, qkvb, C_, C_, C_, TC3, lamb, vT, val_out);

  flash_mfma<<<dim3(16, H_, B_), 256, 0, stream>>>(qkvb, vT);

  gemm_mfma<false, false><<<dim3(C_ / 128, (B_ * T_) / 128), 256, 0, stream>>>(
      qkvb + 2 * C_, WprojT, bproj, out, C_, TC3, C_, C_,
      nullptr, nullptr, nullptr);
}

// Round 13
// 290.759 us; speedup vs baseline: 1.1263x; 1.0018x over previous
//
#include <hip/hip_runtime.h>
#include <math.h>

// Problem constants (B,T,C,H) = (4, 2048, 1024, 16), D = 64.
#define B_   4
#define T_   2048
#define C_   1024
#define H_   16
#define D_   64
#define TC3  3072   // 3*C

typedef __attribute__((ext_vector_type(8))) short short8;
typedef __attribute__((ext_vector_type(4))) short short4b;
typedef __attribute__((ext_vector_type(8))) unsigned short ushortv8;
typedef __attribute__((ext_vector_type(4))) float f32x4;
typedef __attribute__((ext_vector_type(4))) __bf16 bf16x4;

__device__ __forceinline__ float bf2f(unsigned short u) {
  unsigned int x = ((unsigned int)u) << 16;
  float f; __builtin_memcpy(&f, &x, 4); return f;
}
__device__ __forceinline__ unsigned short f2bf(float f) {   // round-nearest-even
  unsigned int x; __builtin_memcpy(&x, &f, 4);
  x += 0x7fff + ((x >> 16) & 1);
  return (unsigned short)(x >> 16);
}

#define MFMA32(a, b, c) __builtin_amdgcn_mfma_f32_16x16x32_bf16(a, b, c, 0, 0, 0)
#if __has_builtin(__builtin_amdgcn_mfma_f32_16x16x16_bf16)
#define MFMA16(a, b, c) __builtin_amdgcn_mfma_f32_16x16x16_bf16(a, b, c, 0, 0, 0)
#else
#define MFMA16(a, b, c) __builtin_amdgcn_mfma_f32_16x16x16bf16_1k(a, b, c, 0, 0, 0)
#endif

#define GLOAD_LDS(gp, lp) __builtin_amdgcn_global_load_lds( \
    (const __attribute__((address_space(1))) unsigned int*)(gp), \
    (__attribute__((address_space(3))) unsigned int*)(lp), 16, 0, 0)

// ---------------------------------------------------------------------------
// Legacy prep kernels — no longer launched (merged into prep_kernel, R13).
// Definitions kept to minimize TU/regalloc perturbation of flash (rule #19).
// ---------------------------------------------------------------------------
__global__ __launch_bounds__(256)
void convert_bf16(const float* __restrict__ x, unsigned short* __restrict__ xb) {
  const size_t i = ((size_t)blockIdx.x * 256 + threadIdx.x) * 8;
  float4 f0 = *(const float4*)(x + i);
  float4 f1 = *(const float4*)(x + i + 4);
  ushortv8 u = { f2bf(f0.x), f2bf(f0.y), f2bf(f0.z), f2bf(f0.w),
                 f2bf(f1.x), f2bf(f1.y), f2bf(f1.z), f2bf(f1.w) };
  *(ushortv8*)(xb + i) = u;
}

__global__ __launch_bounds__(256)
void transpose_bf16(const float* __restrict__ W, unsigned short* __restrict__ WT,
                    int K, int N) {
  __shared__ float tile[64][65];
  const int k0 = blockIdx.y * 64, n0 = blockIdx.x * 64;
  const int r = threadIdx.x >> 4, c4 = (threadIdx.x & 15) * 4;
#pragma unroll
  for (int p = 0; p < 4; ++p) {
    int kk = p * 16 + r;
    float4 v = *(const float4*)(W + (size_t)(k0 + kk) * N + n0 + c4);
    tile[kk][c4 + 0] = v.x; tile[kk][c4 + 1] = v.y;
    tile[kk][c4 + 2] = v.z; tile[kk][c4 + 3] = v.w;
  }
  __syncthreads();
#pragma unroll
  for (int p = 0; p < 4; ++p) {
    int nn = p * 16 + r;
    ushort4 o = { f2bf(tile[c4 + 0][nn]), f2bf(tile[c4 + 1][nn]),
                  f2bf(tile[c4 + 2][nn]), f2bf(tile[c4 + 3][nn]) };
    *(ushort4*)(WT + (size_t)(n0 + nn) * K + k0 + c4) = o;
  }
}

// ---------------------------------------------------------------------------
// Merged prep (R13): x f32->bf16 convert (blocks 0..4095), Wqkv transpose
// (blocks 4096..4863, 48x16 tiles), Wproj transpose (blocks 4864..5119,
// 16x16 tiles). One launch instead of three; whole-block role branch.
// ---------------------------------------------------------------------------
__global__ __launch_bounds__(256)
void prep_kernel(const float* __restrict__ x, unsigned short* __restrict__ xb,
                 const float* __restrict__ Wqkv, unsigned short* __restrict__ WqkvT,
                 const float* __restrict__ Wproj, unsigned short* __restrict__ WprojT) {
  __shared__ float tile[64][65];
  const int bid = blockIdx.x;
  if (bid < 4096) {
    const size_t i = ((size_t)bid * 256 + threadIdx.x) * 8;
    float4 f0 = *(const float4*)(x + i);
    float4 f1 = *(const float4*)(x + i + 4);
    ushortv8 u = { f2bf(f0.x), f2bf(f0.y), f2bf(f0.z), f2bf(f0.w),
                   f2bf(f1.x), f2bf(f1.y), f2bf(f1.z), f2bf(f1.w) };
    *(ushortv8*)(xb + i) = u;
    return;
  }
  const float* W; unsigned short* WT; int N, bx, by;
  if (bid < 4096 + 768) {
    const int t = bid - 4096;
    W = Wqkv; WT = WqkvT; N = TC3; bx = t % 48; by = t / 48;
  } else {
    const int t = bid - 4864;
    W = Wproj; WT = WprojT; N = C_; bx = t & 15; by = t >> 4;
  }
  const int K = C_;
  const int k0 = by * 64, n0 = bx * 64;
  const int r = threadIdx.x >> 4, c4 = (threadIdx.x & 15) * 4;
#pragma unroll
  for (int p = 0; p < 4; ++p) {
    int kk = p * 16 + r;
    float4 v = *(const float4*)(W + (size_t)(k0 + kk) * N + n0 + c4);
    tile[kk][c4 + 0] = v.x; tile[kk][c4 + 1] = v.y;
    tile[kk][c4 + 2] = v.z; tile[kk][c4 + 3] = v.w;
  }
  __syncthreads();
#pragma unroll
  for (int p = 0; p < 4; ++p) {
    int nn = p * 16 + r;
    ushort4 o = { f2bf(tile[c4 + 0][nn]), f2bf(tile[c4 + 1][nn]),
                  f2bf(tile[c4 + 2][nn]), f2bf(tile[c4 + 3][nn]) };
    *(ushort4*)(WT + (size_t)(n0 + nn) * K + k0 + c4) = o;
  }
}

// ---------------------------------------------------------------------------
// bf16 MFMA GEMM (validated R3-R12). A bf16 via global_load_lds.
// R13: bijective XCD-aware block swizzle (T1, m157/m204 form) — consecutive
// linear block ids (which share A m-panels) map to the same XCD's L2 chunk.
// Both grids are %8==0 (GEMM1 1536, GEMM2 512) so the simple form is
// bijective. Operands are L3-fit but NOT per-XCD-L2-fit (A 16.8MB, B 6.3MB
// vs 4MB/XCD) — the regime where swizzle recovers L2 reuse.
// FUSE_QKV (GEMM1 only):
//  * q/k tiles (n0 < 2C): bias + per-head RMSNorm + RoPE on the f32 acc
//    (validated R9-R12; flash applies SCL_ itself).
//  * v tiles (n0 >= 2C): bias + lamb -> valOut f32 direct + vT bf16 via
//    in-LDS transpose (validated R12). qkvb v-columns never written.
// ---------------------------------------------------------------------------
template<bool OUT_BF16, bool FUSE_QKV>
__global__ __launch_bounds__(256)
void gemm_mfma(const unsigned short* __restrict__ Ab,
               const unsigned short* __restrict__ Bt,
               const float* __restrict__ bias, void* __restrict__ Cv,
               int K, int lda, int ldb, int ldc,
               const float* __restrict__ lambp,
               unsigned short* __restrict__ vT,
               float* __restrict__ valOut) {
  __shared__ unsigned short SH[2 * 128 * 64];   // As | Bs (aliased by v-epilogue)
  unsigned short* As = SH;
  unsigned short* Bs = SH + 128 * 64;
  const int tid = threadIdx.x;
  const int l = tid & 63, w = tid >> 6;

  // XCD-aware bijective swizzle (R13)
  int bx, by;
  {
    const int nx = gridDim.x;
    const int nwg = nx * gridDim.y;
    const int qq = nwg >> 3;                       // nwg % 8 == 0
    const int lin = (int)blockIdx.y * nx + (int)blockIdx.x;
    const int swz = (lin & 7) * qq + (lin >> 3);
    bx = swz % nx; by = swz / nx;
  }
  const int m0 = by * 128, n0 = bx * 128;
  const int wm = (w & 1) * 64, wn = (w >> 1) * 64;
  const int fr = l & 15, g = l >> 4;

  f32x4 acc[4][4];
#pragma unroll
  for (int i = 0; i < 4; ++i)
#pragma unroll
    for (int j = 0; j < 4; ++j) acc[i][j] = (f32x4)0.f;

  const int gr = l >> 3;
  const int gc = (l & 7) ^ gr;

  for (int kt = 0; kt < K; kt += 64) {
    __syncthreads();
#pragma unroll
    for (int q = 0; q < 4; ++q) {
      int rr = (w * 4 + q) * 8 + gr;
      GLOAD_LDS(Ab + (size_t)(m0 + rr) * lda + kt + gc * 8,
                &As[(w * 4 + q) * 512]);
      GLOAD_LDS(Bt + (size_t)(n0 + rr) * ldb + kt + gc * 8,
                &Bs[(w * 4 + q) * 512]);
    }
    __syncthreads();

#pragma unroll
    for (int s = 0; s < 2; ++s) {
      const int cofs = (((s * 4 + g) ^ (fr & 7)) << 3);
      short8 a[4], b[4];
#pragma unroll
      for (int i = 0; i < 4; ++i)
        a[i] = *(const short8*)&As[(wm + i * 16 + fr) * 64 + cofs];
#pragma unroll
      for (int j = 0; j < 4; ++j)
        b[j] = *(const short8*)&Bs[(wn + j * 16 + fr) * 64 + cofs];
#pragma unroll
      for (int i = 0; i < 4; ++i)
#pragma unroll
        for (int j = 0; j < 4; ++j)
          acc[i][j] = MFMA32(a[i], b[j], acc[i][j]);
    }
  }

  if (FUSE_QKV && n0 < 2 * C_) {
    // ---- fused bias + RMSNorm + RoPE epilogue (q/k tiles) ----
    float bvj[4];
#pragma unroll
    for (int j = 0; j < 4; ++j) bvj[j] = bias[n0 + wn + j * 16 + fr];
#pragma unroll
    for (int i = 0; i < 4; ++i)
#pragma unroll
      for (int j = 0; j < 4; ++j)
#pragma unroll
        for (int rg = 0; rg < 4; ++rg) acc[i][j][rg] += bvj[j];

    float invf[2];
#pragma unroll
    for (int jp = 0; jp < 2; ++jp)
      invf[jp] = __builtin_amdgcn_exp2f(-13.2877123795494f *
                                        (float)(2 * (jp * 16 + fr)) *
                                        (1.0f / 64.0f));
#pragma unroll
    for (int i = 0; i < 4; ++i) {
#pragma unroll
      for (int rg = 0; rg < 4; ++rg) {
        float ss = 0.f;
#pragma unroll
        for (int j = 0; j < 4; ++j) ss += acc[i][j][rg] * acc[i][j][rg];
        ss += __shfl_xor(ss, 1); ss += __shfl_xor(ss, 2);
        ss += __shfl_xor(ss, 4); ss += __shfl_xor(ss, 8);
        const float s = 1.0f / sqrtf(ss * (1.0f / 64.0f) + 1e-6f);
        const int m = m0 + wm + i * 16 + g * 4 + rg;
        const float t = (float)(m & (T_ - 1));
#pragma unroll
        for (int jp = 0; jp < 2; ++jp) {
          float x1 = acc[i][jp][rg] * s;
          float x2 = acc[i][jp + 2][rg] * s;
          float ang = t * invf[jp];
          float cs = __cosf(ang);
          float sn = __sinf(ang);
          acc[i][jp][rg]     = x1 * cs + x2 * sn;
          acc[i][jp + 2][rg] = x2 * cs - x1 * sn;
        }
      }
    }
#pragma unroll
    for (int j = 0; j < 4; ++j) {
      const int n = n0 + wn + j * 16 + fr;
#pragma unroll
      for (int i = 0; i < 4; ++i)
#pragma unroll
        for (int rg = 0; rg < 4; ++rg) {
          const int m = m0 + wm + i * 16 + g * 4 + rg;
          ((unsigned short*)Cv)[(size_t)m * ldc + n] = f2bf(acc[i][j][rg]);
        }
    }
    return;
  }

  if (FUSE_QKV) {
    // ---- fused V epilogue (n0 >= 2C): bias + lamb -> valOut f32 + vT bf16 ----
    const float lamb = lambp[0];
    const int bb  = m0 >> 11;            // T_ = 2048; block spans one b
    const int t0b = m0 & (T_ - 1);       // block-local t base
    const int h0  = (n0 - 2 * C_) >> 6;  // 2 heads per 128-wide tile
    const int hh  = h0 + (wn >> 6);      // this wave's head (j*16+fr < 64)
    float bvj[4];
#pragma unroll
    for (int j = 0; j < 4; ++j) bvj[j] = bias[n0 + wn + j * 16 + fr];
#pragma unroll
    for (int i = 0; i < 4; ++i)
#pragma unroll
      for (int j = 0; j < 4; ++j)
#pragma unroll
        for (int rg = 0; rg < 4; ++rg) {
          float v = acc[i][j][rg] + bvj[j];
          acc[i][j][rg] = (1.f - lamb) * v + lamb * v;
        }

    // valOut (B,H,T,D) f32 — 16 consecutive d per 16-lane group
    const size_t vob = (size_t)(bb * H_ + hh) * T_;
#pragma unroll
    for (int i = 0; i < 4; ++i)
#pragma unroll
      for (int rg = 0; rg < 4; ++rg) {
        const int t = t0b + wm + i * 16 + g * 4 + rg;
#pragma unroll
        for (int j = 0; j < 4; ++j)
          valOut[(vob + t) * D_ + j * 16 + fr] = acc[i][j][rg];
      }

    // vT (B,H,D,T) bf16 via LDS transpose; two passes (one per head).
    unsigned short (*tile)[65] = (unsigned short (*)[65])SH;  // 128x65 = 16.6KB
#pragma unroll
    for (int hp = 0; hp < 2; ++hp) {
      __syncthreads();                    // As/Bs reads (or prev pass) done
      if ((wn >> 6) == hp) {
#pragma unroll
        for (int i = 0; i < 4; ++i)
#pragma unroll
          for (int j = 0; j < 4; ++j)
#pragma unroll
            for (int rg = 0; rg < 4; ++rg)
              tile[wm + i * 16 + g * 4 + rg][j * 16 + fr] =
                  f2bf(acc[i][j][rg]);
      }
      __syncthreads();
      // 256 threads: d = tid>>2 (0..63), t-chunk = (tid&3)*32 (32 shorts each)
      const int d  = tid >> 2;
      const int tc = (tid & 3) * 32;
      unsigned short* dst =
          vT + ((size_t)(bb * H_ + h0 + hp) * D_ + d) * T_ + t0b + tc;
#pragma unroll
      for (int c8 = 0; c8 < 4; ++c8) {
        ushortv8 o8;
#pragma unroll
        for (int e = 0; e < 8; ++e) o8[e] = tile[tc + c8 * 8 + e][d];
        *(ushortv8*)(dst + c8 * 8) = o8;
      }
    }
    return;
  }

  // ---- plain epilogue (GEMM2) ----
#pragma unroll
  for (int j = 0; j < 4; ++j) {
    const int n = n0 + wn + j * 16 + fr;
    const float bv = bias[n];
#pragma unroll
    for (int i = 0; i < 4; ++i) {
#pragma unroll
      for (int rg = 0; rg < 4; ++rg) {
        const int m = m0 + wm + i * 16 + g * 4 + rg;
        float v = acc[i][j][rg] + bv;
        if (OUT_BF16) ((unsigned short*)Cv)[(size_t)m * ldc + n] = f2bf(v);
        else          ((float*)Cv)[(size_t)m * ldc + n] = v;
      }
    }
  }
}

// ---------------------------------------------------------------------------
// V transpose kernel — NO LONGER LAUNCHED (fused into GEMM1's v epilogue,
// R12). Definition kept to minimize TU/regalloc perturbation of flash.
// ---------------------------------------------------------------------------
__global__ __launch_bounds__(256)
void vtrans_kernel(const unsigned short* __restrict__ qkv,
                   const float* __restrict__ lambp,
                   unsigned short* __restrict__ vT,
                   float* __restrict__ valOut) {
  __shared__ float tile[64][65];
  const int t0 = blockIdx.x * 64;
  const int head = blockIdx.y;             // b*H + h
  const int b = head >> 4, h = head & 15;
  const float lamb = lambp[0];
  const int r = threadIdx.x >> 4, c4 = (threadIdx.x & 15) * 4;
#pragma unroll
  for (int p = 0; p < 4; ++p) {
    int tt = p * 16 + r;
    ushort4 raw = *(const ushort4*)(
        qkv + (size_t)(b * T_ + t0 + tt) * TC3 + 2 * C_ + h * 64 + c4);
    float4 f;
    f.x = (1.f - lamb) * bf2f(raw.x) + lamb * bf2f(raw.x);
    f.y = (1.f - lamb) * bf2f(raw.y) + lamb * bf2f(raw.y);
    f.z = (1.f - lamb) * bf2f(raw.z) + lamb * bf2f(raw.z);
    f.w = (1.f - lamb) * bf2f(raw.w) + lamb * bf2f(raw.w);
    tile[tt][c4 + 0] = f.x; tile[tt][c4 + 1] = f.y;
    tile[tt][c4 + 2] = f.z; tile[tt][c4 + 3] = f.w;
    *(float4*)(valOut + ((size_t)head * T_ + t0 + tt) * D_ + c4) = f;
  }
  __syncthreads();
#pragma unroll
  for (int p = 0; p < 4; ++p) {
    int d = p * 16 + r;
    ushort4 o = { f2bf(tile[c4 + 0][d]), f2bf(tile[c4 + 1][d]),
                  f2bf(tile[c4 + 2][d]), f2bf(tile[c4 + 3][d]) };
    *(ushort4*)(vT + ((size_t)head * D_ + d) * T_ + t0 + c4) = o;
  }
}

// ---------------------------------------------------------------------------
// MFMA flash attention — v15 (R11, validated 90.6us @ 84 VGPR): EXACT R6
// body + __launch_bounds__(256,6). SOURCE FROZEN — do not touch (rule #19;
// flash dur tracks its VGPR allocation, which is schedule-input-dependent).
// ---------------------------------------------------------------------------
#define SCL_ (0.125f * 1.44269504088896f)   // 1/sqrt(D) * log2(e)

__device__ __forceinline__ void attn_tile(
    const unsigned short* Ks,
    const unsigned short* Vs,
    const short8 (&qf)[2][2], int qrow0 /* q0 + w*32 */, int k0,
    int fr, int quad, int f8,
    float (&l_pt)[2], f32x4 (&o)[2][4]) {
  // ---- S^T = K Q^T : C/D col = q(fr), row = key(quad*4+reg) ----
  f32x4 st[2][4];
#pragma unroll
  for (int i = 0; i < 2; ++i)
#pragma unroll
    for (int j = 0; j < 4; ++j) st[i][j] = (f32x4)0.f;

  __builtin_amdgcn_s_setprio(1);
#pragma unroll
  for (int kc = 0; kc < 2; ++kc) {
    const int cofs = (((kc * 4 + quad) ^ f8) << 3);
#pragma unroll
    for (int j = 0; j < 4; ++j) {
      short8 kf = *(const short8*)&Ks[(j * 16 + fr) * 64 + cofs];
      st[0][j] = MFMA32(kf, qf[kc][0], st[0][j]);
      st[1][j] = MFMA32(kf, qf[kc][1], st[1][j]);
    }
  }
  __builtin_amdgcn_s_setprio(0);

  // ---- softmax (fixed basis, per-lane) + pack P into A-frags ----
  short4b pa[2][4];
#pragma unroll
  for (int i = 0; i < 2; ++i) {
    const int qg = qrow0 + i * 16 + fr;
#pragma unroll
    for (int j = 0; j < 4; ++j) {
      const int kg = k0 + j * 16 + quad * 4;
#pragma unroll
      for (int r = 0; r < 4; ++r) {
        float arg = st[i][j][r] * SCL_;
        if (kg + r > qg) arg = -INFINITY;   // branchless causal mask
        float p = __builtin_amdgcn_exp2f(arg);
        l_pt[i] += p;
        st[i][j][r] = p;
      }
      bf16x4 pb = { (__bf16)st[i][j][0], (__bf16)st[i][j][1],
                    (__bf16)st[i][j][2], (__bf16)st[i][j][3] };
      pa[i][j] = __builtin_bit_cast(short4b, pb);
    }
  }

  // ---- O^T += P V via 16x16x16 MFMA (P in regs, V^T b64 B-frags) ----
  __builtin_amdgcn_s_setprio(1);
#pragma unroll
  for (int c = 0; c < 4; ++c) {
    const int vofs = ((((c * 2 + (quad >> 1)) ^ f8) << 3) + (quad & 1) * 4);
#pragma unroll
    for (int jd = 0; jd < 4; ++jd) {
      short4b vf = *(const short4b*)&Vs[(jd * 16 + fr) * 64 + vofs];
      o[0][jd] = MFMA16(pa[0][c], vf, o[0][jd]);
      o[1][jd] = MFMA16(pa[1][c], vf, o[1][jd]);
    }
  }
  __builtin_amdgcn_s_setprio(0);
}

__device__ __forceinline__ void attn_store(
    unsigned short* __restrict__ qkv, int bT, int h, int qrow0,
    int fr, int quad, float (&l_pt)[2], f32x4 (&o)[2][4]) {
#pragma unroll
  for (int i = 0; i < 2; ++i) {
    float lv = l_pt[i];
    lv += __shfl_xor(lv, 16);
    lv += __shfl_xor(lv, 32);
    float inv = 1.0f / lv;
    float invq[4];
#pragma unroll
    for (int r = 0; r < 4; ++r) invq[r] = __shfl(inv, quad * 4 + r);
#pragma unroll
    for (int jd = 0; jd < 4; ++jd) {
      const int d = jd * 16 + fr;
#pragma unroll
      for (int r = 0; r < 4; ++r) {
        const int row = qrow0 + i * 16 + quad * 4 + r;
        qkv[(size_t)(bT + row) * TC3 + 2 * C_ + h * 64 + d] =
            f2bf(o[i][jd][r] * invq[r]);
      }
    }
  }
}

__global__ __launch_bounds__(256, 6)
void flash_mfma(unsigned short* __restrict__ qkv,
                const unsigned short* __restrict__ vT) {
  __shared__ unsigned short KV[2][2][64 * 64];   // [buf][K=0 / V=1], 32 KB
  // Q (128x64 = 16KB) overlays KV[0] during the prologue only.

  // balanced work mapping: qts {x, 15-x, (x+8)&15, 15-((x+8)&15)} per CU
  const int z = blockIdx.z;
  const int xx = ((int)blockIdx.x + ((z >> 1) << 3)) & 15;
  const int qt = (z & 1) ? (15 - xx) : xx;
  const int b  = z;
  const int h  = blockIdx.y;
  const int bT = b * T_;

  const int tid = threadIdx.x;
  const int w = tid >> 6, l = tid & 63;
  const int fr = l & 15, quad = l >> 4;
  const int q0 = qt * 128;
  const int gr = l >> 3;
  const int gc = (l & 7) ^ gr;
  const int f8 = fr & 7;

#define STAGE(KS, VS, KT) do { \
  const int _k0 = (KT) * 64; \
  _Pragma("unroll") \
  for (int s_ = 0; s_ < 2; ++s_) { \
    int row_ = w * 16 + s_ * 8; \
    GLOAD_LDS(qkv + (size_t)(bT + _k0 + row_ + gr) * TC3 + C_ + h * 64 + gc * 8, \
              &(KS)[row_ * 64]); \
    GLOAD_LDS(vT + ((size_t)(b * H_ + h) * D_ + row_ + gr) * T_ + _k0 + gc * 8, \
              &(VS)[row_ * 64]); \
  } \
} while (0)

  // ---- prologue: Q into KV[0] (linear 8192 shorts), tile0 into KV[1] ----
  unsigned short* Qb = &KV[0][0][0];
#pragma unroll
  for (int s = 0; s < 4; ++s) {
    int rbase = w * 32 + s * 8;   // wave-uniform
    GLOAD_LDS(qkv + (size_t)(bT + q0 + rbase + gr) * TC3 + h * 64 + gc * 8,
              Qb + rbase * 64);
  }
  STAGE(KV[1][0], KV[1][1], 0);
  __syncthreads();   // full drain: Q + tile0 staged

  // hoist iteration-invariant Q fragments (B-operand of S^T MFMA)
  short8 qf[2][2];
#pragma unroll
  for (int kc = 0; kc < 2; ++kc) {
    const int cofs = (((kc * 4 + quad) ^ f8) << 3);
    qf[kc][0] = *(const short8*)&Qb[(w * 32 + fr) * 64 + cofs];
    qf[kc][1] = *(const short8*)&Qb[(w * 32 + 16 + fr) * 64 + cofs];
  }
  __syncthreads();   // all waves done reading Q; KV[0] free for staging

  float l_pt[2] = {0.f, 0.f};
  f32x4 o[2][4];
#pragma unroll
  for (int i = 0; i < 2; ++i)
#pragma unroll
    for (int j = 0; j < 4; ++j) o[i][j] = (f32x4)0.f;

  const int nk = 2 * qt + 2;
  const int qr0 = q0 + w * 32;

  int cur = 1;   // tile0 lives in KV[1]
  for (int kt = 0; kt < nk; ++kt) {
    const int nxt = cur ^ 1;
    if (kt + 1 < nk) {
      STAGE(KV[nxt][0], KV[nxt][1], kt + 1);
      asm volatile("s_waitcnt vmcnt(4)" ::: "memory");   // current tile landed
    } else {
      asm volatile("s_waitcnt vmcnt(0)" ::: "memory");   // last tile: drain
    }
    __builtin_amdgcn_s_barrier();
    asm volatile("" ::: "memory");

    attn_tile(&KV[cur][0][0], &KV[cur][1][0], qf, qr0, kt * 64,
              fr, quad, f8, l_pt, o);

    if (kt + 1 < nk) {           // WAR fence: readers done before next STAGE
      __builtin_amdgcn_s_barrier();
      asm volatile("" ::: "memory");
    }
    cur = nxt;
  }

  // ---- epilogue: reduce l over quads, store O/l (row=q via quad*4+r) ----
  attn_store(qkv, bT, h, qr0, fr, quad, l_pt, o);
#undef STAGE
}

// ---------------------------------------------------------------------------
// Launch. d_in: x, Wqkv, bqkv, Wproj, bproj, lamb.
// d_out: out (B*T*C f32) then value (B*H*T*D f32).
// ws: qkvb 50.3MB | WqkvT 6.3MB | WprojT 2.1MB | vT 16.8MB | xb 16.8MB.
// R13: prep merged into one launch; GEMMs get XCD swizzle.
// ---------------------------------------------------------------------------
extern "C" void kernel_launch(void* const* d_in, const int* in_sizes, int n_in,
                              void* d_out, int out_size, void* d_ws, size_t ws_size,
                              hipStream_t stream) {
  const float* x     = (const float*)d_in[0];
  const float* Wqkv  = (const float*)d_in[1];
  const float* bqkv  = (const float*)d_in[2];
  const float* Wproj = (const float*)d_in[3];
  const float* bproj = (const float*)d_in[4];
  const float* lamb  = (const float*)d_in[5];

  float* out     = (float*)d_out;
  float* val_out = out + (size_t)B_ * T_ * C_;

  unsigned short* qkvb   = (unsigned short*)d_ws;                 // B*T*3C
  unsigned short* WqkvT  = qkvb + (size_t)B_ * T_ * TC3;          // 3C x C
  unsigned short* WprojT = WqkvT + (size_t)TC3 * C_;              // C x C
  unsigned short* vT     = WprojT + (size_t)C_ * C_;              // B*H*D*T
  unsigned short* xb     = vT + (size_t)B_ * H_ * D_ * T_;        // B*T*C

  prep_kernel<<<dim3(4096 + 768 + 256), 256, 0, stream>>>(
      x, xb, Wqkv, WqkvT, Wproj, WprojT);

  gemm_mfma<true, true><<<dim3(TC3 / 128, (B_ * T_) / 128), 256, 0, stream>>>(
      xb, WqkvT, bqkv, qkvb, C_, C_, C_, TC3, lamb, vT, val_out);

  flash_mfma<<<dim3(16, H_, B_), 256, 0, stream>>>(qkvb, vT);

  gemm_mfma<false, false><<<dim3(C_ / 128, (B_ * T_) / 128), 256, 0, stream>>>(
      qkvb + 2 * C_, WprojT, bproj, out, C_, TC3, C_, C_,
      nullptr, nullptr, nullptr);
}